// Round 11
// baseline (2240.675 us; speedup 1.0000x reference)
//
#include <hip/hip_runtime.h>
#include <stdint.h>

#define DDIM 768
#define BROWS 4096
#define S0N 4096
#define DICT 32768
#define KTOT 262144u
#define PREF 2.0f
#define DELTA 4e-3f
#define CAND_CAP 8388608u
#define BAND_CAP 4096

// workspace layout (bytes)
static constexpr size_t OFF_XH   = 0;            // 4096*768*2  = 6 MiB
static constexpr size_t OFF_XL   = 6291456;
static constexpr size_t OFF_W0H  = 12582912;
static constexpr size_t OFF_W0L  = 18874368;
static constexpr size_t OFF_W1H  = 25165824;     // 32768*768*2 = 48 MiB
static constexpr size_t OFF_W1L  = 75497472;     // split region ends 125829120
static constexpr size_t OFF_WDT  = 0;            // bf16 WdT aliases split region (48 MiB)
static constexpr size_t OFF_CTRL = 192937984;    // 128 KiB
static constexpr size_t OFF_ROWC = 193069056;    // 16 KiB
static constexpr size_t OFF_ROWD = 193085440;    // 8 MiB
static constexpr size_t OFF_CAND = 201474048;    // 8M*8 = 64 MiB
static constexpr size_t WS_NEED  = 268582912;

// ctrl u32 layout: [0]=cand_cnt [1]=binT [2]=c1 [3]=H [4]=c_hi [5]=band_cnt [6]=k_rem
// hist1 @ ctrl+256 (2048), hist2 @ ctrl+2304 (4096), band_idx @ ctrl+6400 (4096)
// band_v64 (double[4096]) @ OFF_CTRL+65536 ; extra (uint2[4096]) @ OFF_CTRL+98304

typedef __attribute__((ext_vector_type(8))) short bf16x8;
typedef __attribute__((ext_vector_type(4))) float f32x4;

__device__ __forceinline__ unsigned umin_(unsigned a, unsigned b) { return a < b ? a : b; }
__device__ __forceinline__ float relu_(float v) { return v > 0.f ? v : 0.f; }

__device__ __forceinline__ unsigned short f2bf(float f) {
    union { float f; unsigned u; } v; v.f = f;
    unsigned r = v.u + 0x7FFFu + ((v.u >> 16) & 1u);
    return (unsigned short)(r >> 16);
}
__device__ __forceinline__ float bf2f(unsigned short h) {
    union { float f; unsigned u; } v; v.u = ((unsigned)h) << 16;
    return v.f;
}
__device__ __forceinline__ void split1(float a, short& h, short& l) {
    unsigned short hb = f2bf(a);
    float rem = a - bf2f(hb);
    h = (short)hb;
    l = (short)f2bf(rem);
}

__device__ __forceinline__ void gl16(const void* g, void* l) {
    __builtin_amdgcn_global_load_lds(
        (const __attribute__((address_space(1))) void*)g,
        (__attribute__((address_space(3))) void*)l,
        16, 0, 0);
}

// direct global->VGPR 16B load, compiler-invisible completion (manual vmcnt)
__device__ __forceinline__ bf16x8 gload16(const short* p) {
    bf16x8 r;
    asm volatile("global_load_dwordx4 %0, %1, off" : "=v"(r) : "v"(p) : "memory");
    return r;
}

// ---------------- split xc = x - b_dec into bf16 hi/lo ----------------
__global__ void k_split_x(const float* __restrict__ x, const float* __restrict__ b_dec,
                          short* __restrict__ XH, short* __restrict__ XL) {
    int i = blockIdx.x * 256 + threadIdx.x;           // float4 index, exact grid
    float4 xv = ((const float4*)x)[i];
    int d = (i % (DDIM / 4)) * 4;
    float4 bv = *(const float4*)(b_dec + d);
    float a[4] = {xv.x - bv.x, xv.y - bv.y, xv.z - bv.z, xv.w - bv.w};
    short4 h, lo;
    split1(a[0], h.x, lo.x); split1(a[1], h.y, lo.y);
    split1(a[2], h.z, lo.z); split1(a[3], h.w, lo.w);
    ((short4*)XH)[i] = h;
    ((short4*)XL)[i] = lo;
}

// ---------------- split W into bf16 hi/lo ----------------
__global__ void k_split_w(const float* __restrict__ W, short* __restrict__ H,
                          short* __restrict__ L) {
    int i = blockIdx.x * 256 + threadIdx.x;
    float4 wv = ((const float4*)W)[i];
    short4 h, lo;
    split1(wv.x, h.x, lo.x); split1(wv.y, h.y, lo.y);
    split1(wv.z, h.z, lo.z); split1(wv.w, h.w, lo.w);
    ((short4*)H)[i] = h;
    ((short4*)L)[i] = lo;
}

// ---------------- WdT[j][d] = bf16(Wd[d][j]) ----------------
__global__ void k_transpose(const float* __restrict__ Wd, unsigned short* __restrict__ WdT) {
    __shared__ float tile[32][33];
    int j0 = blockIdx.x * 32, d0 = blockIdx.y * 32;
    int tx = threadIdx.x & 31, ty = threadIdx.x >> 5;   // 32 x 8
#pragma unroll
    for (int i = 0; i < 4; ++i)
        tile[ty + i * 8][tx] = Wd[(size_t)(d0 + ty + i * 8) * DICT + j0 + tx];
    __syncthreads();
#pragma unroll
    for (int i = 0; i < 4; ++i)
        WdT[(size_t)(j0 + ty + i * 8) * DDIM + d0 + tx] = f2bf(tile[tx][ty + i * 8]);
}

// ---------------- fused split-bf16 MFMA GEMM (l1 + gate l0), 256x256, 8-wave ----
// A-OPERANDS FROM GLOBAL->VGPR (LDS-pipe relief): per half each wave loads its
// 8 compute + 2 gate A-frags directly (identical per-lane addresses the old
// staging used -> identical register contents; same global traffic, L2/L3-hot).
// B + G stay LDS-staged (wave-shared): LDS reads 16->6 per wave per half.
// Virtual K = 2304 = 72 halves of K=32. Regions (XH,W1H,W0H)(XH,W1L,W0L)
// (XL,W1H,W0H). LDS: B 4 slots x 16KB @0, G 4 slots x 2KB @65536 = 72KB.
// Per half: barrier | 10 A-gloads | 2-3 B/G gl16 stages for H+3 |
//   vmcnt(3|2) [A landed; stg(H+3) in flight] | sched_barrier |
//   6 ds_reads | setprio(1) 36 MFMA setprio(0) | lgkmcnt(0).
__launch_bounds__(512, 2) __global__
void k_mm(const short* __restrict__ XH, const short* __restrict__ XL,
          const short* __restrict__ WH, const short* __restrict__ WL,
          const short* __restrict__ GH, const short* __restrict__ GL,
          const float* __restrict__ bias1, const float* __restrict__ bias0,
          uint2* __restrict__ cand, unsigned* __restrict__ ctrl) {
    __shared__ __align__(16) char smem[73728];

    const int t = threadIdx.x;
    const int w = t >> 6, l = t & 63;
    const int wm = w >> 2, wn = w & 3;            // 2 x 4 wave grid
    const int lr = l & 15, lk = l >> 4;           // frag row / k-group

    const int nwg = gridDim.x;
    const int bid = blockIdx.x;
    const int swz = (bid & 7) * (nwg >> 3) + (bid >> 3);   // XCD-aware (nwg%8==0)
    const int bm = (swz & 15) << 8;
    const int bn = (swz >> 4) << 8;

    // B/G staging addresses (per-lane global source, linear LDS dest)
    const int a0 = 2 * w, a1 = a0 + 1;
    const unsigned bB0 = (unsigned)(bn + (a0 >> 2) * 64 + (a0 & 3) * 16 + lr) * 768u + (unsigned)(lk * 8);
    const unsigned bB1 = (unsigned)(bn + (a1 >> 2) * 64 + (a1 & 3) * 16 + lr) * 768u + (unsigned)(lk * 8);
    const unsigned gB0 = (unsigned)((bn >> 3) + w * 16 + lr) * 768u + (unsigned)(lk * 8);

    // direct A-load element offsets (this wave's own fragments)
    unsigned aOff[8];
#pragma unroll
    for (int mi = 0; mi < 8; ++mi)
        aOff[mi] = (unsigned)(bm + (wm * 8 + mi) * 16 + lr) * 768u + (unsigned)(lk * 8);
    const unsigned gOff0 = (unsigned)(bm + w * 32 + lr) * 768u + (unsigned)(lk * 8);
    const unsigned gOff1 = gOff0 + 16u * 768u;

    f32x4 acc[8][4];
#pragma unroll
    for (int i = 0; i < 8; ++i)
#pragma unroll
        for (int j = 0; j < 4; ++j) acc[i][j] = (f32x4){0.f, 0.f, 0.f, 0.f};
    f32x4 acc_g[2][2];
#pragma unroll
    for (int i = 0; i < 2; ++i)
#pragma unroll
        for (int j = 0; j < 2; ++j) acc_g[i][j] = (f32x4){0.f, 0.f, 0.f, 0.f};

    // prologue: stage B/G halves 0,1,2 (region 0: W1H/GH, kb = J*32)
#pragma unroll
    for (int J = 0; J < 3; ++J) {
        const unsigned kb = (unsigned)J * 32u;
        char* dB = smem + J * 16384 + a0 * 1024;
        gl16(WH + bB0 + kb, dB);
        gl16(WH + bB1 + kb, dB + 1024);
        if (w < 2) gl16(GH + gB0 + kb, smem + 65536 + J * 2048 + w * 1024);
    }

#pragma unroll 1
    for (int H = 0; H < 72; ++H) {
        __builtin_amdgcn_s_barrier();   // half H-1 slot reads drained (lgkm 0 below)

        // A region/offset for half H
        const short* Ax; unsigned kbA;
        if (H < 24)      { Ax = XH; kbA = (unsigned)H * 32u; }
        else if (H < 48) { Ax = XH; kbA = (unsigned)(H - 24) * 32u; }
        else             { Ax = XL; kbA = (unsigned)(H - 48) * 32u; }

        // issue this half's 10 A-loads (global -> VGPR)
        bf16x8 afn[8], agn0, agn1;
#pragma unroll
        for (int mi = 0; mi < 8; ++mi)
            afn[mi] = gload16(Ax + aOff[mi] + kbA);
        agn0 = gload16(Ax + gOff0 + kbA);
        agn1 = gload16(Ax + gOff1 + kbA);

        // stage B/G for half J = H+3 into slot (J&3)
        const int J = H + 3;
        if (J < 72) {
            const short* Bs; const short* Gs; unsigned kb;
            const int ktJ = J >> 1;
            if (ktJ < 12)      { Bs = WH; Gs = GH; kb = (unsigned)ktJ * 64u; }
            else if (ktJ < 24) { Bs = WL; Gs = GL; kb = (unsigned)(ktJ - 12) * 64u; }
            else               { Bs = WH; Gs = GH; kb = (unsigned)(ktJ - 24) * 64u; }
            kb += (unsigned)(J & 1) * 32u;
            char* dB = smem + (J & 3) * 16384 + a0 * 1024;
            gl16(Bs + bB0 + kb, dB);
            gl16(Bs + bB1 + kb, dB + 1024);
            if (w < 2) gl16(Gs + gB0 + kb, smem + 65536 + (J & 3) * 2048 + w * 1024);
        }

        // counted wait: retire this half's A-loads (and stg<=H+2); keep stg(H+3)
        if (H < 69) {
            if (w < 2) asm volatile("s_waitcnt vmcnt(3)" ::: "memory");
            else       asm volatile("s_waitcnt vmcnt(2)" ::: "memory");
        } else {
            asm volatile("s_waitcnt vmcnt(0)" ::: "memory");
        }
        __builtin_amdgcn_sched_barrier(0);   // rule #18: nothing crosses the wait

        // B/G fragments from LDS slot H&3
        const char* rB = smem + (H & 3) * 16384;
        const char* rG = smem + 65536 + (H & 3) * 2048;
        bf16x8 bfr[4];
#pragma unroll
        for (int nj = 0; nj < 4; ++nj)
            bfr[nj] = *(const bf16x8*)(rB + (wn * 4 + nj) * 1024 + l * 16);
        bf16x8 bg0 = *(const bf16x8*)(rG + l * 16);
        bf16x8 bg1 = *(const bf16x8*)(rG + 1024 + l * 16);

        __builtin_amdgcn_s_setprio(1);
#pragma unroll
        for (int mi = 0; mi < 8; ++mi)
#pragma unroll
            for (int nj = 0; nj < 4; ++nj)
                acc[mi][nj] = __builtin_amdgcn_mfma_f32_16x16x32_bf16(
                    afn[mi], bfr[nj], acc[mi][nj], 0, 0, 0);
        acc_g[0][0] = __builtin_amdgcn_mfma_f32_16x16x32_bf16(agn0, bg0, acc_g[0][0], 0, 0, 0);
        acc_g[0][1] = __builtin_amdgcn_mfma_f32_16x16x32_bf16(agn0, bg1, acc_g[0][1], 0, 0, 0);
        acc_g[1][0] = __builtin_amdgcn_mfma_f32_16x16x32_bf16(agn1, bg0, acc_g[1][0], 0, 0, 0);
        acc_g[1][1] = __builtin_amdgcn_mfma_f32_16x16x32_bf16(agn1, bg1, acc_g[1][1], 0, 0, 0);
        __builtin_amdgcn_s_setprio(0);
        asm volatile("s_waitcnt lgkmcnt(0)" ::: "memory");  // slot reads done pre-barrier
    }
    __syncthreads();

    // gate -> LDS [256][33] f32 ; C/D layout (m89): col = lr, row = lk*4 + r
    float*    gate  = (float*)smem;                 // 33792 B
    unsigned* pscan = (unsigned*)(smem + 36864);    // [513]
    const int s0base = bn >> 3;
#pragma unroll
    for (int ri = 0; ri < 2; ++ri)
#pragma unroll
        for (int ci = 0; ci < 2; ++ci)
#pragma unroll
            for (int r = 0; r < 4; ++r) {
                const int grow = w * 32 + ri * 16 + lk * 4 + r;
                const int gcol = ci * 16 + lr;
                gate[grow * 33 + gcol] = relu_(acc_g[ri][ci][r] + bias0[s0base + gcol]);
            }
    __syncthreads();

    unsigned cnt = 0;
#pragma unroll
    for (int mi = 0; mi < 8; ++mi)
#pragma unroll
        for (int nj = 0; nj < 4; ++nj)
#pragma unroll
            for (int r = 0; r < 4; ++r) {
                const int lrow = wm * 128 + mi * 16 + lk * 4 + r;
                const int lcol = wn * 64 + nj * 16 + lr;
                float v = relu_(acc[mi][nj][r] + bias1[bn + lcol]);
                v *= gate[lrow * 33 + (lcol >> 3)];
                acc[mi][nj][r] = v;
                cnt += (v >= PREF) ? 1u : 0u;
            }
    pscan[t] = cnt;
    __syncthreads();
    for (int s = 1; s < 512; s <<= 1) {
        unsigned v2 = (t >= s) ? pscan[t - s] : 0u;
        __syncthreads();
        pscan[t] += v2;
        __syncthreads();
    }
    if (t == 511) pscan[512] = atomicAdd(&ctrl[0], pscan[511]);
    __syncthreads();
    unsigned off = pscan[512] + pscan[t] - cnt;
#pragma unroll
    for (int mi = 0; mi < 8; ++mi)
#pragma unroll
        for (int nj = 0; nj < 4; ++nj)
#pragma unroll
            for (int r = 0; r < 4; ++r) {
                const float v = acc[mi][nj][r];
                if (v >= PREF) {
                    const int row = bm + wm * 128 + mi * 16 + lk * 4 + r;
                    const int col = bn + wn * 64 + nj * 16 + lr;
                    if (off < CAND_CAP)
                        cand[off] = make_uint2(__float_as_uint(v),
                                               ((unsigned)row << 15) | (unsigned)col);
                    ++off;
                }
            }
}

// ---------------- selection: histograms over candidate float bits ----------------
__global__ void k_hist1(const uint2* __restrict__ cand, unsigned* __restrict__ ctrl) {
    __shared__ unsigned h[2048];
    for (int i = threadIdx.x; i < 2048; i += 256) h[i] = 0;
    __syncthreads();
    unsigned n = umin_(ctrl[0], CAND_CAP);
    for (unsigned i = blockIdx.x * 256 + threadIdx.x; i < n; i += gridDim.x * 256)
        atomicAdd(&h[cand[i].x >> 20], 1u);
    __syncthreads();
    unsigned* hist = ctrl + 256;
    for (int i = threadIdx.x; i < 2048; i += 256)
        if (h[i]) atomicAdd(&hist[i], h[i]);
}

__global__ void k_scan1(unsigned* __restrict__ ctrl) {
    __shared__ unsigned hs[2048];
    __shared__ unsigned cs[256];
    const unsigned* h = ctrl + 256;
    int t = threadIdx.x;
    for (int i = t; i < 2048; i += 256) hs[i] = h[i];
    __syncthreads();
    unsigned s = 0;
    for (int b = 0; b < 8; ++b) s += hs[t * 8 + b];
    cs[t] = s;
    __syncthreads();
    if (t == 0) {
        unsigned cum = 0, T = 0, cb = 0;
        for (int c = 255; c >= 0; --c) {
            if (cum + cs[c] >= KTOT) {
                for (int b = c * 8 + 7; b >= c * 8; --b) {
                    cum += hs[b];
                    if (cum >= KTOT) { T = (unsigned)b; cb = cum - hs[b]; break; }
                }
                break;
            }
            cum += cs[c];
        }
        ctrl[1] = T; ctrl[2] = cb;
    }
}

__global__ void k_hist2(const uint2* __restrict__ cand, unsigned* __restrict__ ctrl) {
    unsigned n = umin_(ctrl[0], CAND_CAP);
    unsigned T = ctrl[1];
    unsigned* hist2 = ctrl + 2304;
    for (unsigned i = blockIdx.x * 256 + threadIdx.x; i < n; i += gridDim.x * 256) {
        unsigned u = cand[i].x;
        if ((u >> 20) == T) atomicAdd(&hist2[(u >> 8) & 0xFFFu], 1u);
    }
}

__global__ void k_scan2(unsigned* __restrict__ ctrl) {
    __shared__ unsigned hs[4096];
    __shared__ unsigned cs[256];
    const unsigned* h = ctrl + 2304;
    int t = threadIdx.x;
    for (int i = t; i < 4096; i += 256) hs[i] = h[i];
    __syncthreads();
    unsigned s = 0;
    for (int b = 0; b < 16; ++b) s += hs[t * 16 + b];
    cs[t] = s;
    __syncthreads();
    if (t == 0) {
        unsigned cum = ctrl[2], T2 = 0;
        for (int c = 255; c >= 0; --c) {
            if (cum + cs[c] >= KTOT) {
                for (int b = c * 16 + 15; b >= c * 16; --b) {
                    cum += hs[b];
                    if (cum >= KTOT) { T2 = (unsigned)b; break; }
                }
                break;
            }
            cum += cs[c];
        }
        ctrl[3] = (ctrl[1] << 12) | T2;   // 24-bit prefix H
    }
}

// fused: count strictly-above band + build their per-row CSR, collect band members
__global__ void k_band_rows(const uint2* __restrict__ cand, unsigned* __restrict__ ctrl,
                            unsigned* __restrict__ rowc, uint2* __restrict__ rowd) {
    __shared__ unsigned lhi;
    if (threadIdx.x == 0) lhi = 0;
    __syncthreads();
    unsigned n = umin_(ctrl[0], CAND_CAP);
    unsigned H = ctrl[3];
    float lo = __uint_as_float(H << 8) - DELTA;
    float hi = __uint_as_float((H + 1u) << 8) + DELTA;
    unsigned* band_idx = ctrl + 6400;
    unsigned my = 0;
    for (unsigned i = blockIdx.x * 256 + threadIdx.x; i < n; i += gridDim.x * 256) {
        uint2 cv = cand[i];
        float v = __uint_as_float(cv.x);
        if (v > hi) {
            ++my;
            unsigned b = cv.y >> 15;
            unsigned p = atomicAdd(&rowc[b], 1u);
            if (p < 256u) rowd[(b << 8) + p] = make_uint2(cv.y & 32767u, cv.x);
        } else if (v >= lo) {
            unsigned p = atomicAdd(&ctrl[5], 1u);
            if (p < BAND_CAP) band_idx[p] = cv.y;
        }
    }
    atomicAdd(&lhi, my);
    __syncthreads();
    if (threadIdx.x == 0 && lhi) atomicAdd(&ctrl[4], lhi);
}

// f64 recompute of band elements (exact-vs-numpy selection values)
__global__ void k_f64(const float* __restrict__ x, const float* __restrict__ b_dec,
                      const float* __restrict__ W0, const float* __restrict__ b0,
                      const float* __restrict__ W1, const float* __restrict__ b1,
                      const unsigned* __restrict__ ctrl, double* __restrict__ band_v) {
    unsigned n = umin_(ctrl[5], BAND_CAP);
    unsigned bi = blockIdx.x;
    if (bi >= n) return;
    const unsigned* band_idx = ctrl + 6400;
    unsigned idx = band_idx[bi];
    int b = idx >> 15, j = idx & 32767, s0 = j >> 3;
    int lane = threadIdx.x;
    const float* xr = x + (size_t)b * DDIM;
    const float* w1 = W1 + (size_t)j * DDIM;
    const float* w0 = W0 + (size_t)s0 * DDIM;
    double d1 = 0.0, d0 = 0.0;
    for (int k = lane; k < DDIM; k += 64) {
        double xv = (double)xr[k] - (double)b_dec[k];
        d1 += xv * (double)w1[k];
        d0 += xv * (double)w0[k];
    }
    for (int off = 32; off; off >>= 1) {
        d1 += __shfl_down(d1, off);
        d0 += __shfl_down(d0, off);
    }
    if (lane == 0) {
        double l1v = d1 + (double)b1[j];  l1v = l1v > 0.0 ? l1v : 0.0;
        double l0v = d0 + (double)b0[s0]; l0v = l0v > 0.0 ? l0v : 0.0;
        band_v[bi] = l1v * l0v;
    }
}

// exact in-band ranking: sort (v64 desc, idx asc) over pow2(n), emit first k_rem
__global__ void k_final(unsigned* __restrict__ ctrl, const double* __restrict__ band_v,
                        uint2* __restrict__ extra) {
    __shared__ unsigned long long skey[BAND_CAP];
    __shared__ unsigned sidx[BAND_CAP];
    int t = threadIdx.x;
    unsigned n = umin_(ctrl[5], BAND_CAP);
    unsigned m = 256; while (m < n) m <<= 1;   // sort size: pow2 >= n (uniform)
    const unsigned* band_idx = ctrl + 6400;
    for (unsigned i = t; i < m; i += 256) {
        if (i < n) {
            skey[i] = (unsigned long long)__double_as_longlong(band_v[i]); // v>=0: monotone bits
            sidx[i] = band_idx[i];
        } else {
            skey[i] = 0ull; sidx[i] = 0xFFFFFFFFu;
        }
    }
    __syncthreads();
    for (unsigned kk = 2; kk <= m; kk <<= 1) {
        for (unsigned jj = kk >> 1; jj > 0; jj >>= 1) {
            for (unsigned i = t; i < m; i += 256) {
                unsigned ixj = i ^ jj;
                if (ixj > i) {
                    unsigned long long ka = skey[i], kb = skey[ixj];
                    unsigned ia = sidx[i], ib = sidx[ixj];
                    bool ab = (ka > kb) || (ka == kb && ia < ib);
                    bool asc = ((i & kk) == 0);
                    if (asc ? !ab : ab) {
                        skey[i] = kb; skey[ixj] = ka;
                        sidx[i] = ib; sidx[ixj] = ia;
                    }
                }
            }
            __syncthreads();
        }
    }
    unsigned c_hi = ctrl[4];
    unsigned k_rem = (c_hi < KTOT) ? (KTOT - c_hi) : 0u;
    if (k_rem > n) k_rem = n;
    if (t == 0) ctrl[6] = k_rem;
    for (unsigned i = t; i < k_rem; i += 256)
        extra[i] = make_uint2(sidx[i],
                              __float_as_uint((float)__longlong_as_double((long long)skey[i])));
}

// per-row CSR build: band-selected
__global__ void k_rows_b(const unsigned* __restrict__ ctrl, const uint2* __restrict__ extra,
                         unsigned* __restrict__ rowc, uint2* __restrict__ rowd) {
    unsigned k_rem = ctrl[6];
    for (unsigned i = blockIdx.x * 256 + threadIdx.x; i < k_rem; i += gridDim.x * 256) {
        unsigned idx = extra[i].x;
        unsigned b = idx >> 15;
        unsigned p = atomicAdd(&rowc[b], 1u);
        if (p < 256u) rowd[(b << 8) + p] = make_uint2(idx & 32767u, extra[i].y);
    }
}

// decode: out[b,:] = b_dec + sum v * bf16(WdT[j,:]); 192 thr x 4 cols (ushort4)
__launch_bounds__(192) __global__
void k_decode(const uint2* __restrict__ rowd, const unsigned* __restrict__ rowc,
              const unsigned short* __restrict__ WdT, const float* __restrict__ b_dec,
              float* __restrict__ out) {
    __shared__ uint2 e[256];
    int b = blockIdx.x, t = threadIdx.x;
    unsigned c = rowc[b]; if (c > 256u) c = 256u;
    for (int i = t; i < (int)c; i += 192) e[i] = rowd[(b << 8) + i];
    __syncthreads();
    float4 a = *(const float4*)(b_dec + 4 * t);
#pragma unroll 8
    for (unsigned i = 0; i < c; ++i) {
        float v = __uint_as_float(e[i].y);
        ushort4 w4 = *(const ushort4*)(WdT + (size_t)e[i].x * DDIM + 4 * t);
        a.x = fmaf(v, bf2f(w4.x), a.x);
        a.y = fmaf(v, bf2f(w4.y), a.y);
        a.z = fmaf(v, bf2f(w4.z), a.z);
        a.w = fmaf(v, bf2f(w4.w), a.w);
    }
    *(float4*)(out + (size_t)b * DDIM + 4 * t) = a;
}

extern "C" void kernel_launch(void* const* d_in, const int* in_sizes, int n_in,
                              void* d_out, int out_size, void* d_ws, size_t ws_size,
                              hipStream_t stream) {
    const float* x     = (const float*)d_in[0];
    const float* W0    = (const float*)d_in[1];
    const float* b0    = (const float*)d_in[2];
    const float* W1    = (const float*)d_in[3];
    const float* b1    = (const float*)d_in[4];
    const float* Wd    = (const float*)d_in[5];
    const float* b_dec = (const float*)d_in[6];
    float* out = (float*)d_out;

    if (ws_size < WS_NEED) {   // insufficient workspace: fail cleanly
        hipMemsetAsync(d_out, 0, (size_t)out_size * sizeof(float), stream);
        return;
    }

    char* ws = (char*)d_ws;
    short*          XH     = (short*)(ws + OFF_XH);
    short*          XL     = (short*)(ws + OFF_XL);
    short*          W0H    = (short*)(ws + OFF_W0H);
    short*          W0L    = (short*)(ws + OFF_W0L);
    short*          W1H    = (short*)(ws + OFF_W1H);
    short*          W1L    = (short*)(ws + OFF_W1L);
    unsigned short* WdT    = (unsigned short*)(ws + OFF_WDT);  // aliases split region
    unsigned*       ctrl   = (unsigned*)(ws + OFF_CTRL);
    double*         band_v = (double*)(ws + OFF_CTRL + 65536);
    uint2*          extra  = (uint2*)(ws + OFF_CTRL + 98304);
    unsigned*       rowc   = (unsigned*)(ws + OFF_ROWC);
    uint2*          rowd   = (uint2*)(ws + OFF_ROWD);
    uint2*          cand   = (uint2*)(ws + OFF_CAND);

    hipMemsetAsync(ctrl, 0, 6400 * sizeof(unsigned), stream);
    hipMemsetAsync(rowc, 0, BROWS * sizeof(unsigned), stream);

    k_split_x<<<(BROWS * DDIM / 4) / 256, 256, 0, stream>>>(x, b_dec, XH, XL);
    k_split_w<<<(S0N * DDIM / 4) / 256, 256, 0, stream>>>(W0, W0H, W0L);
    k_split_w<<<(DICT * DDIM / 4) / 256, 256, 0, stream>>>(W1, W1H, W1L);

    k_mm<<<(DICT / 256) * 16, 512, 0, stream>>>(XH, XL, W1H, W1L, W0H, W0L, b1, b0, cand, ctrl);

    // split region is dead now; WdT (bf16) aliases it
    k_transpose<<<dim3(DICT / 32, DDIM / 32), 256, 0, stream>>>(Wd, WdT);

    k_hist1<<<1024, 256, 0, stream>>>(cand, ctrl);
    k_scan1<<<1, 256, 0, stream>>>(ctrl);
    k_hist2<<<1024, 256, 0, stream>>>(cand, ctrl);
    k_scan2<<<1, 256, 0, stream>>>(ctrl);
    k_band_rows<<<1024, 256, 0, stream>>>(cand, ctrl, rowc, rowd);
    k_f64<<<BAND_CAP, 64, 0, stream>>>(x, b_dec, W0, b0, W1, b1, ctrl, band_v);
    k_final<<<1, 256, 0, stream>>>(ctrl, band_v, extra);
    k_rows_b<<<32, 256, 0, stream>>>(ctrl, extra, rowc, rowd);

    k_decode<<<BROWS, 192, 0, stream>>>(rowd, rowc, WdT, b_dec, out);
}

// Round 12
// 1186.316 us; speedup vs baseline: 1.8888x; 1.8888x over previous
//
#include <hip/hip_runtime.h>
#include <stdint.h>

#define DDIM 768
#define BROWS 4096
#define S0N 4096
#define DICT 32768
#define KTOT 262144u
#define PREF 2.0f
#define DELTA 4e-3f
#define CAND_CAP 8388608u
#define BAND_CAP 4096

// workspace layout (bytes)
static constexpr size_t OFF_XH   = 0;            // 4096*768*2  = 6 MiB
static constexpr size_t OFF_XL   = 6291456;
static constexpr size_t OFF_W0H  = 12582912;
static constexpr size_t OFF_W0L  = 18874368;
static constexpr size_t OFF_W1H  = 25165824;     // 32768*768*2 = 48 MiB
static constexpr size_t OFF_W1L  = 75497472;     // split region ends 125829120
static constexpr size_t OFF_WDT  = 0;            // bf16 WdT aliases split region (48 MiB)
static constexpr size_t OFF_CTRL = 192937984;    // 128 KiB
static constexpr size_t OFF_ROWC = 193069056;    // 16 KiB
static constexpr size_t OFF_ROWD = 193085440;    // 8 MiB
static constexpr size_t OFF_CAND = 201474048;    // 8M*8 = 64 MiB
static constexpr size_t WS_NEED  = 268582912;

// ctrl u32 layout: [0]=cand_cnt [1]=binT [2]=c1 [3]=H [4]=c_hi [5]=band_cnt [6]=k_rem
// hist1 @ ctrl+256 (2048), hist2 @ ctrl+2304 (4096), band_idx @ ctrl+6400 (4096)
// band_v64 (double[4096]) @ OFF_CTRL+65536 ; extra (uint2[4096]) @ OFF_CTRL+98304

typedef __attribute__((ext_vector_type(8))) short bf16x8;
typedef __attribute__((ext_vector_type(4))) float f32x4;

__device__ __forceinline__ unsigned umin_(unsigned a, unsigned b) { return a < b ? a : b; }
__device__ __forceinline__ float relu_(float v) { return v > 0.f ? v : 0.f; }

__device__ __forceinline__ unsigned short f2bf(float f) {
    union { float f; unsigned u; } v; v.f = f;
    unsigned r = v.u + 0x7FFFu + ((v.u >> 16) & 1u);
    return (unsigned short)(r >> 16);
}
__device__ __forceinline__ float bf2f(unsigned short h) {
    union { float f; unsigned u; } v; v.u = ((unsigned)h) << 16;
    return v.f;
}
__device__ __forceinline__ void split1(float a, short& h, short& l) {
    unsigned short hb = f2bf(a);
    float rem = a - bf2f(hb);
    h = (short)hb;
    l = (short)f2bf(rem);
}

__device__ __forceinline__ void gl16(const void* g, void* l) {
    __builtin_amdgcn_global_load_lds(
        (const __attribute__((address_space(1))) void*)g,
        (__attribute__((address_space(3))) void*)l,
        16, 0, 0);
}

// ---------------- split xc = x - b_dec into bf16 hi/lo ----------------
__global__ void k_split_x(const float* __restrict__ x, const float* __restrict__ b_dec,
                          short* __restrict__ XH, short* __restrict__ XL) {
    int i = blockIdx.x * 256 + threadIdx.x;           // float4 index, exact grid
    float4 xv = ((const float4*)x)[i];
    int d = (i % (DDIM / 4)) * 4;
    float4 bv = *(const float4*)(b_dec + d);
    float a[4] = {xv.x - bv.x, xv.y - bv.y, xv.z - bv.z, xv.w - bv.w};
    short4 h, lo;
    split1(a[0], h.x, lo.x); split1(a[1], h.y, lo.y);
    split1(a[2], h.z, lo.z); split1(a[3], h.w, lo.w);
    ((short4*)XH)[i] = h;
    ((short4*)XL)[i] = lo;
}

// ---------------- split W into bf16 hi/lo ----------------
__global__ void k_split_w(const float* __restrict__ W, short* __restrict__ H,
                          short* __restrict__ L) {
    int i = blockIdx.x * 256 + threadIdx.x;
    float4 wv = ((const float4*)W)[i];
    short4 h, lo;
    split1(wv.x, h.x, lo.x); split1(wv.y, h.y, lo.y);
    split1(wv.z, h.z, lo.z); split1(wv.w, h.w, lo.w);
    ((short4*)H)[i] = h;
    ((short4*)L)[i] = lo;
}

// ---------------- WdT[j][d] = bf16(Wd[d][j]) ----------------
__global__ void k_transpose(const float* __restrict__ Wd, unsigned short* __restrict__ WdT) {
    __shared__ float tile[32][33];
    int j0 = blockIdx.x * 32, d0 = blockIdx.y * 32;
    int tx = threadIdx.x & 31, ty = threadIdx.x >> 5;   // 32 x 8
#pragma unroll
    for (int i = 0; i < 4; ++i)
        tile[ty + i * 8][tx] = Wd[(size_t)(d0 + ty + i * 8) * DICT + j0 + tx];
    __syncthreads();
#pragma unroll
    for (int i = 0; i < 4; ++i)
        WdT[(size_t)(j0 + ty + i * 8) * DDIM + d0 + tx] = f2bf(tile[tx][ty + i * 8]);
}

// ---------------- fused split-bf16 MFMA GEMM (l1 + gate l0), 256x256, 8-wave ----
// R10-proven pipeline (851us) + gate-A dedup: the gate MFMA's A-operands are a
// SUBSET of the compute A-fragments already in registers. Gate rows for wave
// (wm,wn) are wm*128 + wn*32, so its two gate A-frags equal af[2wn],af[2wn+1]
// of phase A (wn<2) or phase B (wn>=2) -> the 2 ag ds_reads are deleted
// (14->12 LDS reads/wave/half). Wave-uniform branch, static indices.
// Virtual K = 2304 = 72 halves of K=32. Regions (XH,W1H,W0H)(XH,W1L,W0L)
// (XL,W1H,W0H). LDS: A 4x16K @0, B 4x16K @65536, G 4x2K @131072.
// Per half: counted vmcnt (w<2: 10/5/0, else 8/4/0) + barrier, 2 lockstep phases.
__launch_bounds__(512, 2) __global__
void k_mm(const short* __restrict__ XH, const short* __restrict__ XL,
          const short* __restrict__ WH, const short* __restrict__ WL,
          const short* __restrict__ GH, const short* __restrict__ GL,
          const float* __restrict__ bias1, const float* __restrict__ bias0,
          uint2* __restrict__ cand, unsigned* __restrict__ ctrl) {
    __shared__ __align__(16) char smem[139264];

    const int t = threadIdx.x;
    const int w = t >> 6, l = t & 63;
    const int wm = w >> 2, wn = w & 3;            // 2 x 4 wave grid
    const int lr = l & 15, lk = l >> 4;           // frag row / k-group

    const int nwg = gridDim.x;
    const int bid = blockIdx.x;
    const int swz = (bid & 7) * (nwg >> 3) + (bid >> 3);   // XCD-aware (nwg%8==0)
    const int bm = (swz & 15) << 8;
    const int bn = (swz >> 4) << 8;

    // this wave stages A-blocks {2w,2w+1} and B-blocks {2w,2w+1}; waves 0,1 also G
    const int a0 = 2 * w, a1 = a0 + 1;
    const unsigned aB0 = (unsigned)(bm + (a0 >> 3) * 128 + (a0 & 7) * 16 + lr) * 768u + (unsigned)(lk * 8);
    const unsigned aB1 = (unsigned)(bm + (a1 >> 3) * 128 + (a1 & 7) * 16 + lr) * 768u + (unsigned)(lk * 8);
    const unsigned bB0 = (unsigned)(bn + (a0 >> 2) * 64 + (a0 & 3) * 16 + lr) * 768u + (unsigned)(lk * 8);
    const unsigned bB1 = (unsigned)(bn + (a1 >> 2) * 64 + (a1 & 3) * 16 + lr) * 768u + (unsigned)(lk * 8);
    const unsigned gB0 = (unsigned)((bn >> 3) + w * 16 + lr) * 768u + (unsigned)(lk * 8);

    f32x4 acc[8][4];
#pragma unroll
    for (int i = 0; i < 8; ++i)
#pragma unroll
        for (int j = 0; j < 4; ++j) acc[i][j] = (f32x4){0.f, 0.f, 0.f, 0.f};
    f32x4 acc_g[2][2];
#pragma unroll
    for (int i = 0; i < 2; ++i)
#pragma unroll
        for (int j = 0; j < 2; ++j) acc_g[i][j] = (f32x4){0.f, 0.f, 0.f, 0.f};

    // prologue: stage halves 0,1,2 (all region 0: XH/WH/GH, kb = J*32)
#pragma unroll
    for (int J = 0; J < 3; ++J) {
        const unsigned kb = (unsigned)J * 32u;
        char* dA = smem + J * 16384 + a0 * 1024;
        char* dB = smem + 65536 + J * 16384 + a0 * 1024;
        gl16(XH + aB0 + kb, dA);
        gl16(XH + aB1 + kb, dA + 1024);
        gl16(WH + bB0 + kb, dB);
        gl16(WH + bB1 + kb, dB + 1024);
        if (w < 2) gl16(GH + gB0 + kb, smem + 131072 + J * 2048 + w * 1024);
    }

#pragma unroll 1
    for (int H = 0; H < 72; ++H) {
        if (w < 2) {
            if (H < 70)       asm volatile("s_waitcnt vmcnt(10)" ::: "memory");
            else if (H == 70) asm volatile("s_waitcnt vmcnt(5)" ::: "memory");
            else              asm volatile("s_waitcnt vmcnt(0)" ::: "memory");
        } else {
            if (H < 70)       asm volatile("s_waitcnt vmcnt(8)" ::: "memory");
            else if (H == 70) asm volatile("s_waitcnt vmcnt(4)" ::: "memory");
            else              asm volatile("s_waitcnt vmcnt(0)" ::: "memory");
        }
        __builtin_amdgcn_s_barrier();   // all waves' half-H loads landed; slot (H-1)&3 free

        const char* rA = smem + (H & 3) * 16384;
        const char* rB = smem + 65536 + (H & 3) * 16384;
        const char* rG = smem + 131072 + (H & 3) * 2048;

        // stage target: half J = H+3
        const int J = H + 3;
        const short* As = XH; const short* Bs = WH; const short* Gs = GH; unsigned kb = 0;
        char* dA = nullptr; char* dB = nullptr; char* dG = nullptr;
        const bool hj = J < 72;
        if (hj) {
            const int ktJ = J >> 1;
            if (ktJ < 12)      { As = XH; Bs = WH; Gs = GH; kb = (unsigned)ktJ * 64u; }
            else if (ktJ < 24) { As = XH; Bs = WL; Gs = GL; kb = (unsigned)(ktJ - 12) * 64u; }
            else               { As = XL; Bs = WH; Gs = GH; kb = (unsigned)(ktJ - 24) * 64u; }
            kb += (unsigned)(J & 1) * 32u;
            dA = smem + (J & 3) * 16384 + a0 * 1024;
            dB = smem + 65536 + (J & 3) * 16384 + a0 * 1024;
            dG = smem + 131072 + (J & 3) * 2048 + w * 1024;
        }

        // ---- phase A: 4 B + 4 A + 2 G reads | stage A-pair+G | barrier | MFMA ----
        bf16x8 bfr[4], af[4], bg0, bg1;
#pragma unroll
        for (int nj = 0; nj < 4; ++nj)
            bfr[nj] = *(const bf16x8*)(rB + (wn * 4 + nj) * 1024 + l * 16);
#pragma unroll
        for (int m2 = 0; m2 < 4; ++m2)
            af[m2] = *(const bf16x8*)(rA + (wm * 8 + m2) * 1024 + l * 16);
        bg0 = *(const bf16x8*)(rG + l * 16);
        bg1 = *(const bf16x8*)(rG + 1024 + l * 16);
        if (hj) {
            gl16(As + aB0 + kb, dA); gl16(As + aB1 + kb, dA + 1024);
            if (w < 2) gl16(Gs + gB0 + kb, dG);
        }
        __builtin_amdgcn_sched_barrier(0);
        __builtin_amdgcn_s_barrier();
        asm volatile("s_waitcnt lgkmcnt(0)" ::: "memory");
        __builtin_amdgcn_sched_barrier(0);
        __builtin_amdgcn_s_setprio(1);
#pragma unroll
        for (int m2 = 0; m2 < 4; ++m2)
#pragma unroll
            for (int nj = 0; nj < 4; ++nj)
                acc[m2][nj] = __builtin_amdgcn_mfma_f32_16x16x32_bf16(
                    af[m2], bfr[nj], acc[m2][nj], 0, 0, 0);
        if (wn == 0) {        // gate rows wm*128+0..31 = blocks wm*8+0,+1 = af[0],af[1]
            acc_g[0][0] = __builtin_amdgcn_mfma_f32_16x16x32_bf16(af[0], bg0, acc_g[0][0], 0, 0, 0);
            acc_g[0][1] = __builtin_amdgcn_mfma_f32_16x16x32_bf16(af[0], bg1, acc_g[0][1], 0, 0, 0);
            acc_g[1][0] = __builtin_amdgcn_mfma_f32_16x16x32_bf16(af[1], bg0, acc_g[1][0], 0, 0, 0);
            acc_g[1][1] = __builtin_amdgcn_mfma_f32_16x16x32_bf16(af[1], bg1, acc_g[1][1], 0, 0, 0);
        } else if (wn == 1) { // blocks wm*8+2,+3 = af[2],af[3]
            acc_g[0][0] = __builtin_amdgcn_mfma_f32_16x16x32_bf16(af[2], bg0, acc_g[0][0], 0, 0, 0);
            acc_g[0][1] = __builtin_amdgcn_mfma_f32_16x16x32_bf16(af[2], bg1, acc_g[0][1], 0, 0, 0);
            acc_g[1][0] = __builtin_amdgcn_mfma_f32_16x16x32_bf16(af[3], bg0, acc_g[1][0], 0, 0, 0);
            acc_g[1][1] = __builtin_amdgcn_mfma_f32_16x16x32_bf16(af[3], bg1, acc_g[1][1], 0, 0, 0);
        }
        __builtin_amdgcn_s_setprio(0);
        __builtin_amdgcn_s_barrier();

        // ---- phase B: 4 A reads | stage B-pair | barrier | MFMA ----
#pragma unroll
        for (int m2 = 0; m2 < 4; ++m2)
            af[m2] = *(const bf16x8*)(rA + (wm * 8 + 4 + m2) * 1024 + l * 16);
        if (hj) { gl16(Bs + bB0 + kb, dB); gl16(Bs + bB1 + kb, dB + 1024); }
        __builtin_amdgcn_sched_barrier(0);
        __builtin_amdgcn_s_barrier();
        asm volatile("s_waitcnt lgkmcnt(0)" ::: "memory");
        __builtin_amdgcn_sched_barrier(0);
        __builtin_amdgcn_s_setprio(1);
#pragma unroll
        for (int m2 = 0; m2 < 4; ++m2)
#pragma unroll
            for (int nj = 0; nj < 4; ++nj)
                acc[4 + m2][nj] = __builtin_amdgcn_mfma_f32_16x16x32_bf16(
                    af[m2], bfr[nj], acc[4 + m2][nj], 0, 0, 0);
        if (wn == 2) {        // gate rows wm*128+64..95 = blocks wm*8+4,+5 = af[0],af[1]
            acc_g[0][0] = __builtin_amdgcn_mfma_f32_16x16x32_bf16(af[0], bg0, acc_g[0][0], 0, 0, 0);
            acc_g[0][1] = __builtin_amdgcn_mfma_f32_16x16x32_bf16(af[0], bg1, acc_g[0][1], 0, 0, 0);
            acc_g[1][0] = __builtin_amdgcn_mfma_f32_16x16x32_bf16(af[1], bg0, acc_g[1][0], 0, 0, 0);
            acc_g[1][1] = __builtin_amdgcn_mfma_f32_16x16x32_bf16(af[1], bg1, acc_g[1][1], 0, 0, 0);
        } else if (wn == 3) { // blocks wm*8+6,+7 = af[2],af[3]
            acc_g[0][0] = __builtin_amdgcn_mfma_f32_16x16x32_bf16(af[2], bg0, acc_g[0][0], 0, 0, 0);
            acc_g[0][1] = __builtin_amdgcn_mfma_f32_16x16x32_bf16(af[2], bg1, acc_g[0][1], 0, 0, 0);
            acc_g[1][0] = __builtin_amdgcn_mfma_f32_16x16x32_bf16(af[3], bg0, acc_g[1][0], 0, 0, 0);
            acc_g[1][1] = __builtin_amdgcn_mfma_f32_16x16x32_bf16(af[3], bg1, acc_g[1][1], 0, 0, 0);
        }
        __builtin_amdgcn_s_setprio(0);
        __builtin_amdgcn_s_barrier();
    }
    __syncthreads();

    // gate -> LDS [256][33] f32 ; gate rows for wave = wm*128 + wn*32
    // C/D layout (m89-verified): col = lr, row = lk*4 + r
    float*    gate  = (float*)smem;                 // 33792 B
    unsigned* pscan = (unsigned*)(smem + 36864);    // [513]
    const int s0base = bn >> 3;
#pragma unroll
    for (int ri = 0; ri < 2; ++ri)
#pragma unroll
        for (int ci = 0; ci < 2; ++ci)
#pragma unroll
            for (int r = 0; r < 4; ++r) {
                const int grow = wm * 128 + wn * 32 + ri * 16 + lk * 4 + r;
                const int gcol = ci * 16 + lr;
                gate[grow * 33 + gcol] = relu_(acc_g[ri][ci][r] + bias0[s0base + gcol]);
            }
    __syncthreads();

    unsigned cnt = 0;
#pragma unroll
    for (int mi = 0; mi < 8; ++mi)
#pragma unroll
        for (int nj = 0; nj < 4; ++nj)
#pragma unroll
            for (int r = 0; r < 4; ++r) {
                const int lrow = wm * 128 + mi * 16 + lk * 4 + r;
                const int lcol = wn * 64 + nj * 16 + lr;
                float v = relu_(acc[mi][nj][r] + bias1[bn + lcol]);
                v *= gate[lrow * 33 + (lcol >> 3)];
                acc[mi][nj][r] = v;
                cnt += (v >= PREF) ? 1u : 0u;
            }
    pscan[t] = cnt;
    __syncthreads();
    for (int s = 1; s < 512; s <<= 1) {
        unsigned v2 = (t >= s) ? pscan[t - s] : 0u;
        __syncthreads();
        pscan[t] += v2;
        __syncthreads();
    }
    if (t == 511) pscan[512] = atomicAdd(&ctrl[0], pscan[511]);
    __syncthreads();
    unsigned off = pscan[512] + pscan[t] - cnt;
#pragma unroll
    for (int mi = 0; mi < 8; ++mi)
#pragma unroll
        for (int nj = 0; nj < 4; ++nj)
#pragma unroll
            for (int r = 0; r < 4; ++r) {
                const float v = acc[mi][nj][r];
                if (v >= PREF) {
                    const int row = bm + wm * 128 + mi * 16 + lk * 4 + r;
                    const int col = bn + wn * 64 + nj * 16 + lr;
                    if (off < CAND_CAP)
                        cand[off] = make_uint2(__float_as_uint(v),
                                               ((unsigned)row << 15) | (unsigned)col);
                    ++off;
                }
            }
}

// ---------------- selection: histograms over candidate float bits ----------------
__global__ void k_hist1(const uint2* __restrict__ cand, unsigned* __restrict__ ctrl) {
    __shared__ unsigned h[2048];
    for (int i = threadIdx.x; i < 2048; i += 256) h[i] = 0;
    __syncthreads();
    unsigned n = umin_(ctrl[0], CAND_CAP);
    for (unsigned i = blockIdx.x * 256 + threadIdx.x; i < n; i += gridDim.x * 256)
        atomicAdd(&h[cand[i].x >> 20], 1u);
    __syncthreads();
    unsigned* hist = ctrl + 256;
    for (int i = threadIdx.x; i < 2048; i += 256)
        if (h[i]) atomicAdd(&hist[i], h[i]);
}

__global__ void k_scan1(unsigned* __restrict__ ctrl) {
    __shared__ unsigned hs[2048];
    __shared__ unsigned cs[256];
    const unsigned* h = ctrl + 256;
    int t = threadIdx.x;
    for (int i = t; i < 2048; i += 256) hs[i] = h[i];
    __syncthreads();
    unsigned s = 0;
    for (int b = 0; b < 8; ++b) s += hs[t * 8 + b];
    cs[t] = s;
    __syncthreads();
    if (t == 0) {
        unsigned cum = 0, T = 0, cb = 0;
        for (int c = 255; c >= 0; --c) {
            if (cum + cs[c] >= KTOT) {
                for (int b = c * 8 + 7; b >= c * 8; --b) {
                    cum += hs[b];
                    if (cum >= KTOT) { T = (unsigned)b; cb = cum - hs[b]; break; }
                }
                break;
            }
            cum += cs[c];
        }
        ctrl[1] = T; ctrl[2] = cb;
    }
}

__global__ void k_hist2(const uint2* __restrict__ cand, unsigned* __restrict__ ctrl) {
    unsigned n = umin_(ctrl[0], CAND_CAP);
    unsigned T = ctrl[1];
    unsigned* hist2 = ctrl + 2304;
    for (unsigned i = blockIdx.x * 256 + threadIdx.x; i < n; i += gridDim.x * 256) {
        unsigned u = cand[i].x;
        if ((u >> 20) == T) atomicAdd(&hist2[(u >> 8) & 0xFFFu], 1u);
    }
}

__global__ void k_scan2(unsigned* __restrict__ ctrl) {
    __shared__ unsigned hs[4096];
    __shared__ unsigned cs[256];
    const unsigned* h = ctrl + 2304;
    int t = threadIdx.x;
    for (int i = t; i < 4096; i += 256) hs[i] = h[i];
    __syncthreads();
    unsigned s = 0;
    for (int b = 0; b < 16; ++b) s += hs[t * 16 + b];
    cs[t] = s;
    __syncthreads();
    if (t == 0) {
        unsigned cum = ctrl[2], T2 = 0;
        for (int c = 255; c >= 0; --c) {
            if (cum + cs[c] >= KTOT) {
                for (int b = c * 16 + 15; b >= c * 16; --b) {
                    cum += hs[b];
                    if (cum >= KTOT) { T2 = (unsigned)b; break; }
                }
                break;
            }
            cum += cs[c];
        }
        ctrl[3] = (ctrl[1] << 12) | T2;   // 24-bit prefix H
    }
}

// fused: count strictly-above band + build their per-row CSR, collect band members
__global__ void k_band_rows(const uint2* __restrict__ cand, unsigned* __restrict__ ctrl,
                            unsigned* __restrict__ rowc, uint2* __restrict__ rowd) {
    __shared__ unsigned lhi;
    if (threadIdx.x == 0) lhi = 0;
    __syncthreads();
    unsigned n = umin_(ctrl[0], CAND_CAP);
    unsigned H = ctrl[3];
    float lo = __uint_as_float(H << 8) - DELTA;
    float hi = __uint_as_float((H + 1u) << 8) + DELTA;
    unsigned* band_idx = ctrl + 6400;
    unsigned my = 0;
    for (unsigned i = blockIdx.x * 256 + threadIdx.x; i < n; i += gridDim.x * 256) {
        uint2 cv = cand[i];
        float v = __uint_as_float(cv.x);
        if (v > hi) {
            ++my;
            unsigned b = cv.y >> 15;
            unsigned p = atomicAdd(&rowc[b], 1u);
            if (p < 256u) rowd[(b << 8) + p] = make_uint2(cv.y & 32767u, cv.x);
        } else if (v >= lo) {
            unsigned p = atomicAdd(&ctrl[5], 1u);
            if (p < BAND_CAP) band_idx[p] = cv.y;
        }
    }
    atomicAdd(&lhi, my);
    __syncthreads();
    if (threadIdx.x == 0 && lhi) atomicAdd(&ctrl[4], lhi);
}

// f64 recompute of band elements (exact-vs-numpy selection values)
__global__ void k_f64(const float* __restrict__ x, const float* __restrict__ b_dec,
                      const float* __restrict__ W0, const float* __restrict__ b0,
                      const float* __restrict__ W1, const float* __restrict__ b1,
                      const unsigned* __restrict__ ctrl, double* __restrict__ band_v) {
    unsigned n = umin_(ctrl[5], BAND_CAP);
    unsigned bi = blockIdx.x;
    if (bi >= n) return;
    const unsigned* band_idx = ctrl + 6400;
    unsigned idx = band_idx[bi];
    int b = idx >> 15, j = idx & 32767, s0 = j >> 3;
    int lane = threadIdx.x;
    const float* xr = x + (size_t)b * DDIM;
    const float* w1 = W1 + (size_t)j * DDIM;
    const float* w0 = W0 + (size_t)s0 * DDIM;
    double d1 = 0.0, d0 = 0.0;
    for (int k = lane; k < DDIM; k += 64) {
        double xv = (double)xr[k] - (double)b_dec[k];
        d1 += xv * (double)w1[k];
        d0 += xv * (double)w0[k];
    }
    for (int off = 32; off; off >>= 1) {
        d1 += __shfl_down(d1, off);
        d0 += __shfl_down(d0, off);
    }
    if (lane == 0) {
        double l1v = d1 + (double)b1[j];  l1v = l1v > 0.0 ? l1v : 0.0;
        double l0v = d0 + (double)b0[s0]; l0v = l0v > 0.0 ? l0v : 0.0;
        band_v[bi] = l1v * l0v;
    }
}

// exact in-band ranking: sort (v64 desc, idx asc) over pow2(n), emit first k_rem
__global__ void k_final(unsigned* __restrict__ ctrl, const double* __restrict__ band_v,
                        uint2* __restrict__ extra) {
    __shared__ unsigned long long skey[BAND_CAP];
    __shared__ unsigned sidx[BAND_CAP];
    int t = threadIdx.x;
    unsigned n = umin_(ctrl[5], BAND_CAP);
    unsigned m = 256; while (m < n) m <<= 1;   // sort size: pow2 >= n (uniform)
    const unsigned* band_idx = ctrl + 6400;
    for (unsigned i = t; i < m; i += 256) {
        if (i < n) {
            skey[i] = (unsigned long long)__double_as_longlong(band_v[i]); // v>=0: monotone bits
            sidx[i] = band_idx[i];
        } else {
            skey[i] = 0ull; sidx[i] = 0xFFFFFFFFu;
        }
    }
    __syncthreads();
    for (unsigned kk = 2; kk <= m; kk <<= 1) {
        for (unsigned jj = kk >> 1; jj > 0; jj >>= 1) {
            for (unsigned i = t; i < m; i += 256) {
                unsigned ixj = i ^ jj;
                if (ixj > i) {
                    unsigned long long ka = skey[i], kb = skey[ixj];
                    unsigned ia = sidx[i], ib = sidx[ixj];
                    bool ab = (ka > kb) || (ka == kb && ia < ib);
                    bool asc = ((i & kk) == 0);
                    if (asc ? !ab : ab) {
                        skey[i] = kb; skey[ixj] = ka;
                        sidx[i] = ib; sidx[ixj] = ia;
                    }
                }
            }
            __syncthreads();
        }
    }
    unsigned c_hi = ctrl[4];
    unsigned k_rem = (c_hi < KTOT) ? (KTOT - c_hi) : 0u;
    if (k_rem > n) k_rem = n;
    if (t == 0) ctrl[6] = k_rem;
    for (unsigned i = t; i < k_rem; i += 256)
        extra[i] = make_uint2(sidx[i],
                              __float_as_uint((float)__longlong_as_double((long long)skey[i])));
}

// per-row CSR build: band-selected
__global__ void k_rows_b(const unsigned* __restrict__ ctrl, const uint2* __restrict__ extra,
                         unsigned* __restrict__ rowc, uint2* __restrict__ rowd) {
    unsigned k_rem = ctrl[6];
    for (unsigned i = blockIdx.x * 256 + threadIdx.x; i < k_rem; i += gridDim.x * 256) {
        unsigned idx = extra[i].x;
        unsigned b = idx >> 15;
        unsigned p = atomicAdd(&rowc[b], 1u);
        if (p < 256u) rowd[(b << 8) + p] = make_uint2(idx & 32767u, extra[i].y);
    }
}

// decode: out[b,:] = b_dec + sum v * bf16(WdT[j,:]); 192 thr x 4 cols (ushort4)
__launch_bounds__(192) __global__
void k_decode(const uint2* __restrict__ rowd, const unsigned* __restrict__ rowc,
              const unsigned short* __restrict__ WdT, const float* __restrict__ b_dec,
              float* __restrict__ out) {
    __shared__ uint2 e[256];
    int b = blockIdx.x, t = threadIdx.x;
    unsigned c = rowc[b]; if (c > 256u) c = 256u;
    for (int i = t; i < (int)c; i += 192) e[i] = rowd[(b << 8) + i];
    __syncthreads();
    float4 a = *(const float4*)(b_dec + 4 * t);
#pragma unroll 8
    for (unsigned i = 0; i < c; ++i) {
        float v = __uint_as_float(e[i].y);
        ushort4 w4 = *(const ushort4*)(WdT + (size_t)e[i].x * DDIM + 4 * t);
        a.x = fmaf(v, bf2f(w4.x), a.x);
        a.y = fmaf(v, bf2f(w4.y), a.y);
        a.z = fmaf(v, bf2f(w4.z), a.z);
        a.w = fmaf(v, bf2f(w4.w), a.w);
    }
    *(float4*)(out + (size_t)b * DDIM + 4 * t) = a;
}

extern "C" void kernel_launch(void* const* d_in, const int* in_sizes, int n_in,
                              void* d_out, int out_size, void* d_ws, size_t ws_size,
                              hipStream_t stream) {
    const float* x     = (const float*)d_in[0];
    const float* W0    = (const float*)d_in[1];
    const float* b0    = (const float*)d_in[2];
    const float* W1    = (const float*)d_in[3];
    const float* b1    = (const float*)d_in[4];
    const float* Wd    = (const float*)d_in[5];
    const float* b_dec = (const float*)d_in[6];
    float* out = (float*)d_out;

    if (ws_size < WS_NEED) {   // insufficient workspace: fail cleanly
        hipMemsetAsync(d_out, 0, (size_t)out_size * sizeof(float), stream);
        return;
    }

    char* ws = (char*)d_ws;
    short*          XH     = (short*)(ws + OFF_XH);
    short*          XL     = (short*)(ws + OFF_XL);
    short*          W0H    = (short*)(ws + OFF_W0H);
    short*          W0L    = (short*)(ws + OFF_W0L);
    short*          W1H    = (short*)(ws + OFF_W1H);
    short*          W1L    = (short*)(ws + OFF_W1L);
    unsigned short* WdT    = (unsigned short*)(ws + OFF_WDT);  // aliases split region
    unsigned*       ctrl   = (unsigned*)(ws + OFF_CTRL);
    double*         band_v = (double*)(ws + OFF_CTRL + 65536);
    uint2*          extra  = (uint2*)(ws + OFF_CTRL + 98304);
    unsigned*       rowc   = (unsigned*)(ws + OFF_ROWC);
    uint2*          rowd   = (uint2*)(ws + OFF_ROWD);
    uint2*          cand   = (uint2*)(ws + OFF_CAND);

    hipMemsetAsync(ctrl, 0, 6400 * sizeof(unsigned), stream);
    hipMemsetAsync(rowc, 0, BROWS * sizeof(unsigned), stream);

    k_split_x<<<(BROWS * DDIM / 4) / 256, 256, 0, stream>>>(x, b_dec, XH, XL);
    k_split_w<<<(S0N * DDIM / 4) / 256, 256, 0, stream>>>(W0, W0H, W0L);
    k_split_w<<<(DICT * DDIM / 4) / 256, 256, 0, stream>>>(W1, W1H, W1L);

    k_mm<<<(DICT / 256) * 16, 512, 0, stream>>>(XH, XL, W1H, W1L, W0H, W0L, b1, b0, cand, ctrl);

    // split region is dead now; WdT (bf16) aliases it
    k_transpose<<<dim3(DICT / 32, DDIM / 32), 256, 0, stream>>>(Wd, WdT);

    k_hist1<<<1024, 256, 0, stream>>>(cand, ctrl);
    k_scan1<<<1, 256, 0, stream>>>(ctrl);
    k_hist2<<<1024, 256, 0, stream>>>(cand, ctrl);
    k_scan2<<<1, 256, 0, stream>>>(ctrl);
    k_band_rows<<<1024, 256, 0, stream>>>(cand, ctrl, rowc, rowd);
    k_f64<<<BAND_CAP, 64, 0, stream>>>(x, b_dec, W0, b0, W1, b1, ctrl, band_v);
    k_final<<<1, 256, 0, stream>>>(ctrl, band_v, extra);
    k_rows_b<<<32, 256, 0, stream>>>(ctrl, extra, rowc, rowd);

    k_decode<<<BROWS, 192, 0, stream>>>(rowd, rowc, WdT, b_dec, out);
}

// Round 13
// 1105.249 us; speedup vs baseline: 2.0273x; 1.0733x over previous
//
#include <hip/hip_runtime.h>
#include <stdint.h>

#define DDIM 768
#define BROWS 4096
#define S0N 4096
#define DICT 32768
#define KTOT 262144u
#define PREF 2.0f
#define DELTA 4e-3f
#define CAND_CAP 8388608u
#define BAND_CAP 4096

// workspace layout (bytes)
static constexpr size_t OFF_XH   = 0;            // 4096*768*2  = 6 MiB
static constexpr size_t OFF_XL   = 6291456;
static constexpr size_t OFF_W0H  = 12582912;
static constexpr size_t OFF_W0L  = 18874368;
static constexpr size_t OFF_W1H  = 25165824;     // 32768*768*2 = 48 MiB
static constexpr size_t OFF_W1L  = 75497472;     // split region ends 125829120
static constexpr size_t OFF_WDT  = 0;            // bf16 WdT aliases split region (48 MiB)
static constexpr size_t OFF_CTRL = 192937984;    // 128 KiB
static constexpr size_t OFF_ROWC = 193069056;    // 16 KiB
static constexpr size_t OFF_ROWD = 193085440;    // 8 MiB
static constexpr size_t OFF_CAND = 201474048;    // 8M*8 = 64 MiB
static constexpr size_t WS_NEED  = 268582912;

// ctrl u32 layout: [0]=cand_cnt [1]=binT [2]=c1 [3]=H [4]=c_hi [5]=band_cnt [6]=k_rem
// hist1 @ ctrl+256 (2048), hist2 @ ctrl+2304 (4096), band_idx @ ctrl+6400 (4096)
// band_v64 (double[4096]) @ OFF_CTRL+65536 ; extra (uint2[4096]) @ OFF_CTRL+98304

typedef __attribute__((ext_vector_type(8))) short bf16x8;
typedef __attribute__((ext_vector_type(4))) float f32x4;

__device__ __forceinline__ unsigned umin_(unsigned a, unsigned b) { return a < b ? a : b; }
__device__ __forceinline__ float relu_(float v) { return v > 0.f ? v : 0.f; }

__device__ __forceinline__ unsigned short f2bf(float f) {
    union { float f; unsigned u; } v; v.f = f;
    unsigned r = v.u + 0x7FFFu + ((v.u >> 16) & 1u);
    return (unsigned short)(r >> 16);
}
__device__ __forceinline__ float bf2f(unsigned short h) {
    union { float f; unsigned u; } v; v.u = ((unsigned)h) << 16;
    return v.f;
}
__device__ __forceinline__ void split1(float a, short& h, short& l) {
    unsigned short hb = f2bf(a);
    float rem = a - bf2f(hb);
    h = (short)hb;
    l = (short)f2bf(rem);
}

__device__ __forceinline__ void gl16(const void* g, void* l) {
    __builtin_amdgcn_global_load_lds(
        (const __attribute__((address_space(1))) void*)g,
        (__attribute__((address_space(3))) void*)l,
        16, 0, 0);
}

// ---------------- split xc = x - b_dec into bf16 hi/lo ----------------
__global__ void k_split_x(const float* __restrict__ x, const float* __restrict__ b_dec,
                          short* __restrict__ XH, short* __restrict__ XL) {
    int i = blockIdx.x * 256 + threadIdx.x;           // float4 index, exact grid
    float4 xv = ((const float4*)x)[i];
    int d = (i % (DDIM / 4)) * 4;
    float4 bv = *(const float4*)(b_dec + d);
    float a[4] = {xv.x - bv.x, xv.y - bv.y, xv.z - bv.z, xv.w - bv.w};
    short4 h, lo;
    split1(a[0], h.x, lo.x); split1(a[1], h.y, lo.y);
    split1(a[2], h.z, lo.z); split1(a[3], h.w, lo.w);
    ((short4*)XH)[i] = h;
    ((short4*)XL)[i] = lo;
}

// ---------------- split W into bf16 hi/lo ----------------
__global__ void k_split_w(const float* __restrict__ W, short* __restrict__ H,
                          short* __restrict__ L) {
    int i = blockIdx.x * 256 + threadIdx.x;
    float4 wv = ((const float4*)W)[i];
    short4 h, lo;
    split1(wv.x, h.x, lo.x); split1(wv.y, h.y, lo.y);
    split1(wv.z, h.z, lo.z); split1(wv.w, h.w, lo.w);
    ((short4*)H)[i] = h;
    ((short4*)L)[i] = lo;
}

// ---------------- WdT[j][d] = bf16(Wd[d][j]) ----------------
__global__ void k_transpose(const float* __restrict__ Wd, unsigned short* __restrict__ WdT) {
    __shared__ float tile[32][33];
    int j0 = blockIdx.x * 32, d0 = blockIdx.y * 32;
    int tx = threadIdx.x & 31, ty = threadIdx.x >> 5;   // 32 x 8
#pragma unroll
    for (int i = 0; i < 4; ++i)
        tile[ty + i * 8][tx] = Wd[(size_t)(d0 + ty + i * 8) * DICT + j0 + tx];
    __syncthreads();
#pragma unroll
    for (int i = 0; i < 4; ++i)
        WdT[(size_t)(j0 + ty + i * 8) * DDIM + d0 + tx] = f2bf(tile[tx][ty + i * 8]);
}

// ---------------- fused split-bf16 MFMA GEMM (l1 + gate l0), 256x256, 8-wave ----
// R10 base (851us) with intra-half restructure: ALL 16 ds_reads (both phases'
// operands) + all 5 gl16 stages issued up front, then ONE 36-MFMA cluster with
// NO manual lgkmcnt drain -- the compiler inserts counted lgkmcnt, so phase-B
// operand reads complete in the shadow of phase-A MFMAs (LDS pipe || MFMA pipe).
// 1 barrier/half. WAR ledger: each wave's slot reads are consumed by its MFMAs
// before it reaches the next top-barrier; staging targets slot (H+3)&3 =
// (H-1)&3 whose readers drained during half H-1.
// Virtual K = 2304 = 72 halves of K=32. Regions (XH,W1H,W0H)(XH,W1L,W0L)
// (XL,W1H,W0H). LDS: A 4x16K @0, B 4x16K @65536, G 4x2K @131072.
// Counted vmcnt unchanged (w<2: 10/5/0, else 8/4/0).
__launch_bounds__(512, 2) __global__
void k_mm(const short* __restrict__ XH, const short* __restrict__ XL,
          const short* __restrict__ WH, const short* __restrict__ WL,
          const short* __restrict__ GH, const short* __restrict__ GL,
          const float* __restrict__ bias1, const float* __restrict__ bias0,
          uint2* __restrict__ cand, unsigned* __restrict__ ctrl) {
    __shared__ __align__(16) char smem[139264];

    const int t = threadIdx.x;
    const int w = t >> 6, l = t & 63;
    const int wm = w >> 2, wn = w & 3;            // 2 x 4 wave grid
    const int lr = l & 15, lk = l >> 4;           // frag row / k-group

    const int nwg = gridDim.x;
    const int bid = blockIdx.x;
    const int swz = (bid & 7) * (nwg >> 3) + (bid >> 3);   // XCD-aware (nwg%8==0)
    const int bm = (swz & 15) << 8;
    const int bn = (swz >> 4) << 8;

    // this wave stages A-blocks {2w,2w+1} and B-blocks {2w,2w+1}; waves 0,1 also G
    const int a0 = 2 * w, a1 = a0 + 1;
    const unsigned aB0 = (unsigned)(bm + (a0 >> 3) * 128 + (a0 & 7) * 16 + lr) * 768u + (unsigned)(lk * 8);
    const unsigned aB1 = (unsigned)(bm + (a1 >> 3) * 128 + (a1 & 7) * 16 + lr) * 768u + (unsigned)(lk * 8);
    const unsigned bB0 = (unsigned)(bn + (a0 >> 2) * 64 + (a0 & 3) * 16 + lr) * 768u + (unsigned)(lk * 8);
    const unsigned bB1 = (unsigned)(bn + (a1 >> 2) * 64 + (a1 & 3) * 16 + lr) * 768u + (unsigned)(lk * 8);
    const unsigned gB0 = (unsigned)((bn >> 3) + w * 16 + lr) * 768u + (unsigned)(lk * 8);
    const int cg0 = (w >> 2) * 8 + (w & 3) * 2;   // A-block pair for gate rows [w*32, +32)

    f32x4 acc[8][4];
#pragma unroll
    for (int i = 0; i < 8; ++i)
#pragma unroll
        for (int j = 0; j < 4; ++j) acc[i][j] = (f32x4){0.f, 0.f, 0.f, 0.f};
    f32x4 acc_g[2][2];
#pragma unroll
    for (int i = 0; i < 2; ++i)
#pragma unroll
        for (int j = 0; j < 2; ++j) acc_g[i][j] = (f32x4){0.f, 0.f, 0.f, 0.f};

    // prologue: stage halves 0,1,2 (all region 0: XH/WH/GH, kb = J*32)
#pragma unroll
    for (int J = 0; J < 3; ++J) {
        const unsigned kb = (unsigned)J * 32u;
        char* dA = smem + J * 16384 + a0 * 1024;
        char* dB = smem + 65536 + J * 16384 + a0 * 1024;
        gl16(XH + aB0 + kb, dA);
        gl16(XH + aB1 + kb, dA + 1024);
        gl16(WH + bB0 + kb, dB);
        gl16(WH + bB1 + kb, dB + 1024);
        if (w < 2) gl16(GH + gB0 + kb, smem + 131072 + J * 2048 + w * 1024);
    }

#pragma unroll 1
    for (int H = 0; H < 72; ++H) {
        if (w < 2) {
            if (H < 70)       asm volatile("s_waitcnt vmcnt(10)" ::: "memory");
            else if (H == 70) asm volatile("s_waitcnt vmcnt(5)" ::: "memory");
            else              asm volatile("s_waitcnt vmcnt(0)" ::: "memory");
        } else {
            if (H < 70)       asm volatile("s_waitcnt vmcnt(8)" ::: "memory");
            else if (H == 70) asm volatile("s_waitcnt vmcnt(4)" ::: "memory");
            else              asm volatile("s_waitcnt vmcnt(0)" ::: "memory");
        }
        __builtin_amdgcn_s_barrier();   // all waves' half-H loads landed; slot (H-1)&3 free

        const char* rA = smem + (H & 3) * 16384;
        const char* rB = smem + 65536 + (H & 3) * 16384;
        const char* rG = smem + 131072 + (H & 3) * 2048;

        // stage target: half J = H+3
        const int J = H + 3;
        const short* As = XH; const short* Bs = WH; const short* Gs = GH; unsigned kb = 0;
        char* dA = nullptr; char* dB = nullptr; char* dG = nullptr;
        const bool hj = J < 72;
        if (hj) {
            const int ktJ = J >> 1;
            if (ktJ < 12)      { As = XH; Bs = WH; Gs = GH; kb = (unsigned)ktJ * 64u; }
            else if (ktJ < 24) { As = XH; Bs = WL; Gs = GL; kb = (unsigned)(ktJ - 12) * 64u; }
            else               { As = XL; Bs = WH; Gs = GH; kb = (unsigned)(ktJ - 24) * 64u; }
            kb += (unsigned)(J & 1) * 32u;
            dA = smem + (J & 3) * 16384 + a0 * 1024;
            dB = smem + 65536 + (J & 3) * 16384 + a0 * 1024;
            dG = smem + 131072 + (J & 3) * 2048 + w * 1024;
        }

        // ---- all operand reads (both phases) + all stages, then 36-MFMA cluster ----
        bf16x8 bfr[4], afA[4], afB[4], bg0, bg1, agA, agB;
#pragma unroll
        for (int nj = 0; nj < 4; ++nj)
            bfr[nj] = *(const bf16x8*)(rB + (wn * 4 + nj) * 1024 + l * 16);
#pragma unroll
        for (int m2 = 0; m2 < 4; ++m2)
            afA[m2] = *(const bf16x8*)(rA + (wm * 8 + m2) * 1024 + l * 16);
        bg0 = *(const bf16x8*)(rG + l * 16);
        bg1 = *(const bf16x8*)(rG + 1024 + l * 16);
        agA = *(const bf16x8*)(rA + cg0 * 1024 + l * 16);
        if (hj) {
            gl16(As + aB0 + kb, dA); gl16(As + aB1 + kb, dA + 1024);
            gl16(Bs + bB0 + kb, dB); gl16(Bs + bB1 + kb, dB + 1024);
            if (w < 2) gl16(Gs + gB0 + kb, dG);
        }
#pragma unroll
        for (int m2 = 0; m2 < 4; ++m2)
            afB[m2] = *(const bf16x8*)(rA + (wm * 8 + 4 + m2) * 1024 + l * 16);
        agB = *(const bf16x8*)(rA + (cg0 + 1) * 1024 + l * 16);
        __builtin_amdgcn_sched_barrier(0);   // pin: all issues above, MFMA below

        __builtin_amdgcn_s_setprio(1);
        // phase-A MFMAs (operands = reads 1..11; compiler waits counted lgkmcnt)
#pragma unroll
        for (int m2 = 0; m2 < 4; ++m2)
#pragma unroll
            for (int nj = 0; nj < 4; ++nj)
                acc[m2][nj] = __builtin_amdgcn_mfma_f32_16x16x32_bf16(
                    afA[m2], bfr[nj], acc[m2][nj], 0, 0, 0);
        acc_g[0][0] = __builtin_amdgcn_mfma_f32_16x16x32_bf16(agA, bg0, acc_g[0][0], 0, 0, 0);
        acc_g[0][1] = __builtin_amdgcn_mfma_f32_16x16x32_bf16(agA, bg1, acc_g[0][1], 0, 0, 0);
        // phase-B MFMAs (operands prefetched; completed under phase-A MFMAs)
#pragma unroll
        for (int m2 = 0; m2 < 4; ++m2)
#pragma unroll
            for (int nj = 0; nj < 4; ++nj)
                acc[4 + m2][nj] = __builtin_amdgcn_mfma_f32_16x16x32_bf16(
                    afB[m2], bfr[nj], acc[4 + m2][nj], 0, 0, 0);
        acc_g[1][0] = __builtin_amdgcn_mfma_f32_16x16x32_bf16(agB, bg0, acc_g[1][0], 0, 0, 0);
        acc_g[1][1] = __builtin_amdgcn_mfma_f32_16x16x32_bf16(agB, bg1, acc_g[1][1], 0, 0, 0);
        __builtin_amdgcn_s_setprio(0);
    }
    __syncthreads();

    // gate -> LDS [256][33] f32 ; gate rows for wave = w*32
    // C/D layout (m89-verified): col = lr, row = lk*4 + r
    float*    gate  = (float*)smem;                 // 33792 B
    unsigned* pscan = (unsigned*)(smem + 36864);    // [513]
    const int s0base = bn >> 3;
#pragma unroll
    for (int ri = 0; ri < 2; ++ri)
#pragma unroll
        for (int ci = 0; ci < 2; ++ci)
#pragma unroll
            for (int r = 0; r < 4; ++r) {
                const int grow = w * 32 + ri * 16 + lk * 4 + r;
                const int gcol = ci * 16 + lr;
                gate[grow * 33 + gcol] = relu_(acc_g[ri][ci][r] + bias0[s0base + gcol]);
            }
    __syncthreads();

    unsigned cnt = 0;
#pragma unroll
    for (int mi = 0; mi < 8; ++mi)
#pragma unroll
        for (int nj = 0; nj < 4; ++nj)
#pragma unroll
            for (int r = 0; r < 4; ++r) {
                const int lrow = wm * 128 + mi * 16 + lk * 4 + r;
                const int lcol = wn * 64 + nj * 16 + lr;
                float v = relu_(acc[mi][nj][r] + bias1[bn + lcol]);
                v *= gate[lrow * 33 + (lcol >> 3)];
                acc[mi][nj][r] = v;
                cnt += (v >= PREF) ? 1u : 0u;
            }
    pscan[t] = cnt;
    __syncthreads();
    for (int s = 1; s < 512; s <<= 1) {
        unsigned v2 = (t >= s) ? pscan[t - s] : 0u;
        __syncthreads();
        pscan[t] += v2;
        __syncthreads();
    }
    if (t == 511) pscan[512] = atomicAdd(&ctrl[0], pscan[511]);
    __syncthreads();
    unsigned off = pscan[512] + pscan[t] - cnt;
#pragma unroll
    for (int mi = 0; mi < 8; ++mi)
#pragma unroll
        for (int nj = 0; nj < 4; ++nj)
#pragma unroll
            for (int r = 0; r < 4; ++r) {
                const float v = acc[mi][nj][r];
                if (v >= PREF) {
                    const int row = bm + wm * 128 + mi * 16 + lk * 4 + r;
                    const int col = bn + wn * 64 + nj * 16 + lr;
                    if (off < CAND_CAP)
                        cand[off] = make_uint2(__float_as_uint(v),
                                               ((unsigned)row << 15) | (unsigned)col);
                    ++off;
                }
            }
}

// ---------------- selection: histograms over candidate float bits ----------------
__global__ void k_hist1(const uint2* __restrict__ cand, unsigned* __restrict__ ctrl) {
    __shared__ unsigned h[2048];
    for (int i = threadIdx.x; i < 2048; i += 256) h[i] = 0;
    __syncthreads();
    unsigned n = umin_(ctrl[0], CAND_CAP);
    for (unsigned i = blockIdx.x * 256 + threadIdx.x; i < n; i += gridDim.x * 256)
        atomicAdd(&h[cand[i].x >> 20], 1u);
    __syncthreads();
    unsigned* hist = ctrl + 256;
    for (int i = threadIdx.x; i < 2048; i += 256)
        if (h[i]) atomicAdd(&hist[i], h[i]);
}

__global__ void k_scan1(unsigned* __restrict__ ctrl) {
    __shared__ unsigned hs[2048];
    __shared__ unsigned cs[256];
    const unsigned* h = ctrl + 256;
    int t = threadIdx.x;
    for (int i = t; i < 2048; i += 256) hs[i] = h[i];
    __syncthreads();
    unsigned s = 0;
    for (int b = 0; b < 8; ++b) s += hs[t * 8 + b];
    cs[t] = s;
    __syncthreads();
    if (t == 0) {
        unsigned cum = 0, T = 0, cb = 0;
        for (int c = 255; c >= 0; --c) {
            if (cum + cs[c] >= KTOT) {
                for (int b = c * 8 + 7; b >= c * 8; --b) {
                    cum += hs[b];
                    if (cum >= KTOT) { T = (unsigned)b; cb = cum - hs[b]; break; }
                }
                break;
            }
            cum += cs[c];
        }
        ctrl[1] = T; ctrl[2] = cb;
    }
}

__global__ void k_hist2(const uint2* __restrict__ cand, unsigned* __restrict__ ctrl) {
    unsigned n = umin_(ctrl[0], CAND_CAP);
    unsigned T = ctrl[1];
    unsigned* hist2 = ctrl + 2304;
    for (unsigned i = blockIdx.x * 256 + threadIdx.x; i < n; i += gridDim.x * 256) {
        unsigned u = cand[i].x;
        if ((u >> 20) == T) atomicAdd(&hist2[(u >> 8) & 0xFFFu], 1u);
    }
}

__global__ void k_scan2(unsigned* __restrict__ ctrl) {
    __shared__ unsigned hs[4096];
    __shared__ unsigned cs[256];
    const unsigned* h = ctrl + 2304;
    int t = threadIdx.x;
    for (int i = t; i < 4096; i += 256) hs[i] = h[i];
    __syncthreads();
    unsigned s = 0;
    for (int b = 0; b < 16; ++b) s += hs[t * 16 + b];
    cs[t] = s;
    __syncthreads();
    if (t == 0) {
        unsigned cum = ctrl[2], T2 = 0;
        for (int c = 255; c >= 0; --c) {
            if (cum + cs[c] >= KTOT) {
                for (int b = c * 16 + 15; b >= c * 16; --b) {
                    cum += hs[b];
                    if (cum >= KTOT) { T2 = (unsigned)b; break; }
                }
                break;
            }
            cum += cs[c];
        }
        ctrl[3] = (ctrl[1] << 12) | T2;   // 24-bit prefix H
    }
}

// fused: count strictly-above band + build their per-row CSR, collect band members
__global__ void k_band_rows(const uint2* __restrict__ cand, unsigned* __restrict__ ctrl,
                            unsigned* __restrict__ rowc, uint2* __restrict__ rowd) {
    __shared__ unsigned lhi;
    if (threadIdx.x == 0) lhi = 0;
    __syncthreads();
    unsigned n = umin_(ctrl[0], CAND_CAP);
    unsigned H = ctrl[3];
    float lo = __uint_as_float(H << 8) - DELTA;
    float hi = __uint_as_float((H + 1u) << 8) + DELTA;
    unsigned* band_idx = ctrl + 6400;
    unsigned my = 0;
    for (unsigned i = blockIdx.x * 256 + threadIdx.x; i < n; i += gridDim.x * 256) {
        uint2 cv = cand[i];
        float v = __uint_as_float(cv.x);
        if (v > hi) {
            ++my;
            unsigned b = cv.y >> 15;
            unsigned p = atomicAdd(&rowc[b], 1u);
            if (p < 256u) rowd[(b << 8) + p] = make_uint2(cv.y & 32767u, cv.x);
        } else if (v >= lo) {
            unsigned p = atomicAdd(&ctrl[5], 1u);
            if (p < BAND_CAP) band_idx[p] = cv.y;
        }
    }
    atomicAdd(&lhi, my);
    __syncthreads();
    if (threadIdx.x == 0 && lhi) atomicAdd(&ctrl[4], lhi);
}

// f64 recompute of band elements (exact-vs-numpy selection values)
__global__ void k_f64(const float* __restrict__ x, const float* __restrict__ b_dec,
                      const float* __restrict__ W0, const float* __restrict__ b0,
                      const float* __restrict__ W1, const float* __restrict__ b1,
                      const unsigned* __restrict__ ctrl, double* __restrict__ band_v) {
    unsigned n = umin_(ctrl[5], BAND_CAP);
    unsigned bi = blockIdx.x;
    if (bi >= n) return;
    const unsigned* band_idx = ctrl + 6400;
    unsigned idx = band_idx[bi];
    int b = idx >> 15, j = idx & 32767, s0 = j >> 3;
    int lane = threadIdx.x;
    const float* xr = x + (size_t)b * DDIM;
    const float* w1 = W1 + (size_t)j * DDIM;
    const float* w0 = W0 + (size_t)s0 * DDIM;
    double d1 = 0.0, d0 = 0.0;
    for (int k = lane; k < DDIM; k += 64) {
        double xv = (double)xr[k] - (double)b_dec[k];
        d1 += xv * (double)w1[k];
        d0 += xv * (double)w0[k];
    }
    for (int off = 32; off; off >>= 1) {
        d1 += __shfl_down(d1, off);
        d0 += __shfl_down(d0, off);
    }
    if (lane == 0) {
        double l1v = d1 + (double)b1[j];  l1v = l1v > 0.0 ? l1v : 0.0;
        double l0v = d0 + (double)b0[s0]; l0v = l0v > 0.0 ? l0v : 0.0;
        band_v[bi] = l1v * l0v;
    }
}

// exact in-band ranking: sort (v64 desc, idx asc) over pow2(n), emit first k_rem
__global__ void k_final(unsigned* __restrict__ ctrl, const double* __restrict__ band_v,
                        uint2* __restrict__ extra) {
    __shared__ unsigned long long skey[BAND_CAP];
    __shared__ unsigned sidx[BAND_CAP];
    int t = threadIdx.x;
    unsigned n = umin_(ctrl[5], BAND_CAP);
    unsigned m = 256; while (m < n) m <<= 1;   // sort size: pow2 >= n (uniform)
    const unsigned* band_idx = ctrl + 6400;
    for (unsigned i = t; i < m; i += 256) {
        if (i < n) {
            skey[i] = (unsigned long long)__double_as_longlong(band_v[i]); // v>=0: monotone bits
            sidx[i] = band_idx[i];
        } else {
            skey[i] = 0ull; sidx[i] = 0xFFFFFFFFu;
        }
    }
    __syncthreads();
    for (unsigned kk = 2; kk <= m; kk <<= 1) {
        for (unsigned jj = kk >> 1; jj > 0; jj >>= 1) {
            for (unsigned i = t; i < m; i += 256) {
                unsigned ixj = i ^ jj;
                if (ixj > i) {
                    unsigned long long ka = skey[i], kb = skey[ixj];
                    unsigned ia = sidx[i], ib = sidx[ixj];
                    bool ab = (ka > kb) || (ka == kb && ia < ib);
                    bool asc = ((i & kk) == 0);
                    if (asc ? !ab : ab) {
                        skey[i] = kb; skey[ixj] = ka;
                        sidx[i] = ib; sidx[ixj] = ia;
                    }
                }
            }
            __syncthreads();
        }
    }
    unsigned c_hi = ctrl[4];
    unsigned k_rem = (c_hi < KTOT) ? (KTOT - c_hi) : 0u;
    if (k_rem > n) k_rem = n;
    if (t == 0) ctrl[6] = k_rem;
    for (unsigned i = t; i < k_rem; i += 256)
        extra[i] = make_uint2(sidx[i],
                              __float_as_uint((float)__longlong_as_double((long long)skey[i])));
}

// per-row CSR build: band-selected
__global__ void k_rows_b(const unsigned* __restrict__ ctrl, const uint2* __restrict__ extra,
                         unsigned* __restrict__ rowc, uint2* __restrict__ rowd) {
    unsigned k_rem = ctrl[6];
    for (unsigned i = blockIdx.x * 256 + threadIdx.x; i < k_rem; i += gridDim.x * 256) {
        unsigned idx = extra[i].x;
        unsigned b = idx >> 15;
        unsigned p = atomicAdd(&rowc[b], 1u);
        if (p < 256u) rowd[(b << 8) + p] = make_uint2(idx & 32767u, extra[i].y);
    }
}

// decode: out[b,:] = b_dec + sum v * bf16(WdT[j,:]); 192 thr x 4 cols (ushort4)
__launch_bounds__(192) __global__
void k_decode(const uint2* __restrict__ rowd, const unsigned* __restrict__ rowc,
              const unsigned short* __restrict__ WdT, const float* __restrict__ b_dec,
              float* __restrict__ out) {
    __shared__ uint2 e[256];
    int b = blockIdx.x, t = threadIdx.x;
    unsigned c = rowc[b]; if (c > 256u) c = 256u;
    for (int i = t; i < (int)c; i += 192) e[i] = rowd[(b << 8) + i];
    __syncthreads();
    float4 a = *(const float4*)(b_dec + 4 * t);
#pragma unroll 8
    for (unsigned i = 0; i < c; ++i) {
        float v = __uint_as_float(e[i].y);
        ushort4 w4 = *(const ushort4*)(WdT + (size_t)e[i].x * DDIM + 4 * t);
        a.x = fmaf(v, bf2f(w4.x), a.x);
        a.y = fmaf(v, bf2f(w4.y), a.y);
        a.z = fmaf(v, bf2f(w4.z), a.z);
        a.w = fmaf(v, bf2f(w4.w), a.w);
    }
    *(float4*)(out + (size_t)b * DDIM + 4 * t) = a;
}

extern "C" void kernel_launch(void* const* d_in, const int* in_sizes, int n_in,
                              void* d_out, int out_size, void* d_ws, size_t ws_size,
                              hipStream_t stream) {
    const float* x     = (const float*)d_in[0];
    const float* W0    = (const float*)d_in[1];
    const float* b0    = (const float*)d_in[2];
    const float* W1    = (const float*)d_in[3];
    const float* b1    = (const float*)d_in[4];
    const float* Wd    = (const float*)d_in[5];
    const float* b_dec = (const float*)d_in[6];
    float* out = (float*)d_out;

    if (ws_size < WS_NEED) {   // insufficient workspace: fail cleanly
        hipMemsetAsync(d_out, 0, (size_t)out_size * sizeof(float), stream);
        return;
    }

    char* ws = (char*)d_ws;
    short*          XH     = (short*)(ws + OFF_XH);
    short*          XL     = (short*)(ws + OFF_XL);
    short*          W0H    = (short*)(ws + OFF_W0H);
    short*          W0L    = (short*)(ws + OFF_W0L);
    short*          W1H    = (short*)(ws + OFF_W1H);
    short*          W1L    = (short*)(ws + OFF_W1L);
    unsigned short* WdT    = (unsigned short*)(ws + OFF_WDT);  // aliases split region
    unsigned*       ctrl   = (unsigned*)(ws + OFF_CTRL);
    double*         band_v = (double*)(ws + OFF_CTRL + 65536);
    uint2*          extra  = (uint2*)(ws + OFF_CTRL + 98304);
    unsigned*       rowc   = (unsigned*)(ws + OFF_ROWC);
    uint2*          rowd   = (uint2*)(ws + OFF_ROWD);
    uint2*          cand   = (uint2*)(ws + OFF_CAND);

    hipMemsetAsync(ctrl, 0, 6400 * sizeof(unsigned), stream);
    hipMemsetAsync(rowc, 0, BROWS * sizeof(unsigned), stream);

    k_split_x<<<(BROWS * DDIM / 4) / 256, 256, 0, stream>>>(x, b_dec, XH, XL);
    k_split_w<<<(S0N * DDIM / 4) / 256, 256, 0, stream>>>(W0, W0H, W0L);
    k_split_w<<<(DICT * DDIM / 4) / 256, 256, 0, stream>>>(W1, W1H, W1L);

    k_mm<<<(DICT / 256) * 16, 512, 0, stream>>>(XH, XL, W1H, W1L, W0H, W0L, b1, b0, cand, ctrl);

    // split region is dead now; WdT (bf16) aliases it
    k_transpose<<<dim3(DICT / 32, DDIM / 32), 256, 0, stream>>>(Wd, WdT);

    k_hist1<<<1024, 256, 0, stream>>>(cand, ctrl);
    k_scan1<<<1, 256, 0, stream>>>(ctrl);
    k_hist2<<<1024, 256, 0, stream>>>(cand, ctrl);
    k_scan2<<<1, 256, 0, stream>>>(ctrl);
    k_band_rows<<<1024, 256, 0, stream>>>(cand, ctrl, rowc, rowd);
    k_f64<<<BAND_CAP, 64, 0, stream>>>(x, b_dec, W0, b0, W1, b1, ctrl, band_v);
    k_final<<<1, 256, 0, stream>>>(ctrl, band_v, extra);
    k_rows_b<<<32, 256, 0, stream>>>(ctrl, extra, rowc, rowd);

    k_decode<<<BROWS, 192, 0, stream>>>(rowd, rowc, WdT, b_dec, out);
}

// Round 14
// 1100.644 us; speedup vs baseline: 2.0358x; 1.0042x over previous
//
#include <hip/hip_runtime.h>
#include <stdint.h>

#define DDIM 768
#define BROWS 4096
#define S0N 4096
#define DICT 32768
#define KTOT 262144u
#define PREF 2.0f
#define DELTA 4e-3f
#define CAND_CAP 8388608u
#define BAND_CAP 4096

// workspace layout (bytes)
static constexpr size_t OFF_XH   = 0;            // 4096*768*2  = 6 MiB
static constexpr size_t OFF_XL   = 6291456;
static constexpr size_t OFF_W0H  = 12582912;
static constexpr size_t OFF_W0L  = 18874368;
static constexpr size_t OFF_W1H  = 25165824;     // 32768*768*2 = 48 MiB
static constexpr size_t OFF_W1L  = 75497472;     // split region ends 125829120
static constexpr size_t OFF_WDT  = 0;            // bf16 WdT aliases split region (48 MiB)
static constexpr size_t OFF_CTRL = 192937984;    // 128 KiB
static constexpr size_t OFF_ROWC = 193069056;    // 16 KiB
static constexpr size_t OFF_ROWD = 193085440;    // 8 MiB
static constexpr size_t OFF_CAND = 201474048;    // 8M*8 = 64 MiB
static constexpr size_t WS_NEED  = 268582912;

// ctrl u32 layout: [0]=cand_cnt [1]=binT [2]=c1 [3]=H [4]=c_hi [5]=band_cnt [6]=k_rem
// hist1 @ ctrl+256 (2048), hist2 @ ctrl+2304 (4096), band_idx @ ctrl+6400 (4096)
// band_v64 (double[4096]) @ OFF_CTRL+65536

typedef __attribute__((ext_vector_type(8))) short bf16x8;
typedef __attribute__((ext_vector_type(4))) float f32x4;

__device__ __forceinline__ unsigned umin_(unsigned a, unsigned b) { return a < b ? a : b; }
__device__ __forceinline__ float relu_(float v) { return v > 0.f ? v : 0.f; }

__device__ __forceinline__ unsigned short f2bf(float f) {
    union { float f; unsigned u; } v; v.f = f;
    unsigned r = v.u + 0x7FFFu + ((v.u >> 16) & 1u);
    return (unsigned short)(r >> 16);
}
__device__ __forceinline__ float bf2f(unsigned short h) {
    union { float f; unsigned u; } v; v.u = ((unsigned)h) << 16;
    return v.f;
}
__device__ __forceinline__ void split1(float a, short& h, short& l) {
    unsigned short hb = f2bf(a);
    float rem = a - bf2f(hb);
    h = (short)hb;
    l = (short)f2bf(rem);
}

__device__ __forceinline__ void gl16(const void* g, void* l) {
    __builtin_amdgcn_global_load_lds(
        (const __attribute__((address_space(1))) void*)g,
        (__attribute__((address_space(3))) void*)l,
        16, 0, 0);
}

// ---------------- split xc = x - b_dec into bf16 hi/lo ----------------
__global__ void k_split_x(const float* __restrict__ x, const float* __restrict__ b_dec,
                          short* __restrict__ XH, short* __restrict__ XL) {
    int i = blockIdx.x * 256 + threadIdx.x;           // float4 index, exact grid
    float4 xv = ((const float4*)x)[i];
    int d = (i % (DDIM / 4)) * 4;
    float4 bv = *(const float4*)(b_dec + d);
    float a[4] = {xv.x - bv.x, xv.y - bv.y, xv.z - bv.z, xv.w - bv.w};
    short4 h, lo;
    split1(a[0], h.x, lo.x); split1(a[1], h.y, lo.y);
    split1(a[2], h.z, lo.z); split1(a[3], h.w, lo.w);
    ((short4*)XH)[i] = h;
    ((short4*)XL)[i] = lo;
}

// ---------------- split W into bf16 hi/lo ----------------
__global__ void k_split_w(const float* __restrict__ W, short* __restrict__ H,
                          short* __restrict__ L) {
    int i = blockIdx.x * 256 + threadIdx.x;
    float4 wv = ((const float4*)W)[i];
    short4 h, lo;
    split1(wv.x, h.x, lo.x); split1(wv.y, h.y, lo.y);
    split1(wv.z, h.z, lo.z); split1(wv.w, h.w, lo.w);
    ((short4*)H)[i] = h;
    ((short4*)L)[i] = lo;
}

// ---------------- WdT[j][d] = bf16(Wd[d][j]) ----------------
__global__ void k_transpose(const float* __restrict__ Wd, unsigned short* __restrict__ WdT) {
    __shared__ float tile[32][33];
    int j0 = blockIdx.x * 32, d0 = blockIdx.y * 32;
    int tx = threadIdx.x & 31, ty = threadIdx.x >> 5;   // 32 x 8
#pragma unroll
    for (int i = 0; i < 4; ++i)
        tile[ty + i * 8][tx] = Wd[(size_t)(d0 + ty + i * 8) * DICT + j0 + tx];
    __syncthreads();
#pragma unroll
    for (int i = 0; i < 4; ++i)
        WdT[(size_t)(j0 + ty + i * 8) * DDIM + d0 + tx] = f2bf(tile[tx][ty + i * 8]);
}

// ---------------- fused split-bf16 MFMA GEMM (l1 + gate l0), 256x256, 8-wave ----
// R13 structure (810us, MfmaUtil 38%) + gate-A register dedup: gate blocks
// 2w,2w+1 ARE this wave's own af fragments (blocks wm*8 + (w&3)*2, +1), so the
// 2 gate ds_reads are replaced by register reuse via a static wave-uniform
// 4-way branch (register SELECTION differs per wave; MFMA count/position is
// uniform -> no lockstep divergence, unlike R12's phase-split dedup).
// LDS reads: 16 -> 14 per wave per half.
// Per half: counted vmcnt + 1 barrier; ALL reads + stages up front; one
// 36-MFMA cluster, compiler-counted lgkmcnt (phase-B reads land under
// phase-A MFMAs). Regions (XH,W1H,W0H)(XH,W1L,W0L)(XL,W1H,W0H), 72 halves.
// LDS: A 4x16K @0, B 4x16K @65536, G 4x2K @131072.
__launch_bounds__(512, 2) __global__
void k_mm(const short* __restrict__ XH, const short* __restrict__ XL,
          const short* __restrict__ WH, const short* __restrict__ WL,
          const short* __restrict__ GH, const short* __restrict__ GL,
          const float* __restrict__ bias1, const float* __restrict__ bias0,
          uint2* __restrict__ cand, unsigned* __restrict__ ctrl) {
    __shared__ __align__(16) char smem[139264];

    const int t = threadIdx.x;
    const int w = t >> 6, l = t & 63;
    const int wm = w >> 2, wn = w & 3;            // 2 x 4 wave grid
    const int lr = l & 15, lk = l >> 4;           // frag row / k-group

    const int nwg = gridDim.x;
    const int bid = blockIdx.x;
    const int swz = (bid & 7) * (nwg >> 3) + (bid >> 3);   // XCD-aware (nwg%8==0)
    const int bm = (swz & 15) << 8;
    const int bn = (swz >> 4) << 8;

    // this wave stages A-blocks {2w,2w+1} and B-blocks {2w,2w+1}; waves 0,1 also G
    const int a0 = 2 * w, a1 = a0 + 1;
    const unsigned aB0 = (unsigned)(bm + (a0 >> 3) * 128 + (a0 & 7) * 16 + lr) * 768u + (unsigned)(lk * 8);
    const unsigned aB1 = (unsigned)(bm + (a1 >> 3) * 128 + (a1 & 7) * 16 + lr) * 768u + (unsigned)(lk * 8);
    const unsigned bB0 = (unsigned)(bn + (a0 >> 2) * 64 + (a0 & 3) * 16 + lr) * 768u + (unsigned)(lk * 8);
    const unsigned bB1 = (unsigned)(bn + (a1 >> 2) * 64 + (a1 & 3) * 16 + lr) * 768u + (unsigned)(lk * 8);
    const unsigned gB0 = (unsigned)((bn >> 3) + w * 16 + lr) * 768u + (unsigned)(lk * 8);

    f32x4 acc[8][4];
#pragma unroll
    for (int i = 0; i < 8; ++i)
#pragma unroll
        for (int j = 0; j < 4; ++j) acc[i][j] = (f32x4){0.f, 0.f, 0.f, 0.f};
    f32x4 acc_g[2][2];
#pragma unroll
    for (int i = 0; i < 2; ++i)
#pragma unroll
        for (int j = 0; j < 2; ++j) acc_g[i][j] = (f32x4){0.f, 0.f, 0.f, 0.f};

    // prologue: stage halves 0,1,2 (all region 0: XH/WH/GH, kb = J*32)
#pragma unroll
    for (int J = 0; J < 3; ++J) {
        const unsigned kb = (unsigned)J * 32u;
        char* dA = smem + J * 16384 + a0 * 1024;
        char* dB = smem + 65536 + J * 16384 + a0 * 1024;
        gl16(XH + aB0 + kb, dA);
        gl16(XH + aB1 + kb, dA + 1024);
        gl16(WH + bB0 + kb, dB);
        gl16(WH + bB1 + kb, dB + 1024);
        if (w < 2) gl16(GH + gB0 + kb, smem + 131072 + J * 2048 + w * 1024);
    }

#pragma unroll 1
    for (int H = 0; H < 72; ++H) {
        if (w < 2) {
            if (H < 70)       asm volatile("s_waitcnt vmcnt(10)" ::: "memory");
            else if (H == 70) asm volatile("s_waitcnt vmcnt(5)" ::: "memory");
            else              asm volatile("s_waitcnt vmcnt(0)" ::: "memory");
        } else {
            if (H < 70)       asm volatile("s_waitcnt vmcnt(8)" ::: "memory");
            else if (H == 70) asm volatile("s_waitcnt vmcnt(4)" ::: "memory");
            else              asm volatile("s_waitcnt vmcnt(0)" ::: "memory");
        }
        __builtin_amdgcn_s_barrier();   // all waves' half-H loads landed; slot (H-1)&3 free

        const char* rA = smem + (H & 3) * 16384;
        const char* rB = smem + 65536 + (H & 3) * 16384;
        const char* rG = smem + 131072 + (H & 3) * 2048;

        // stage target: half J = H+3
        const int J = H + 3;
        const short* As = XH; const short* Bs = WH; const short* Gs = GH; unsigned kb = 0;
        char* dA = nullptr; char* dB = nullptr; char* dG = nullptr;
        const bool hj = J < 72;
        if (hj) {
            const int ktJ = J >> 1;
            if (ktJ < 12)      { As = XH; Bs = WH; Gs = GH; kb = (unsigned)ktJ * 64u; }
            else if (ktJ < 24) { As = XH; Bs = WL; Gs = GL; kb = (unsigned)(ktJ - 12) * 64u; }
            else               { As = XL; Bs = WH; Gs = GH; kb = (unsigned)(ktJ - 24) * 64u; }
            kb += (unsigned)(J & 1) * 32u;
            dA = smem + (J & 3) * 16384 + a0 * 1024;
            dB = smem + 65536 + (J & 3) * 16384 + a0 * 1024;
            dG = smem + 131072 + (J & 3) * 2048 + w * 1024;
        }

        // ---- all operand reads (14) + all stages, then 36-MFMA cluster ----
        bf16x8 bfr[4], afA[4], afB[4], bg0, bg1;
#pragma unroll
        for (int nj = 0; nj < 4; ++nj)
            bfr[nj] = *(const bf16x8*)(rB + (wn * 4 + nj) * 1024 + l * 16);
#pragma unroll
        for (int m2 = 0; m2 < 4; ++m2)
            afA[m2] = *(const bf16x8*)(rA + (wm * 8 + m2) * 1024 + l * 16);
        bg0 = *(const bf16x8*)(rG + l * 16);
        bg1 = *(const bf16x8*)(rG + 1024 + l * 16);
        if (hj) {
            gl16(As + aB0 + kb, dA); gl16(As + aB1 + kb, dA + 1024);
            gl16(Bs + bB0 + kb, dB); gl16(Bs + bB1 + kb, dB + 1024);
            if (w < 2) gl16(Gs + gB0 + kb, dG);
        }
#pragma unroll
        for (int m2 = 0; m2 < 4; ++m2)
            afB[m2] = *(const bf16x8*)(rA + (wm * 8 + 4 + m2) * 1024 + l * 16);
        __builtin_amdgcn_sched_barrier(0);   // pin: all issues above, MFMA below

        __builtin_amdgcn_s_setprio(1);
#pragma unroll
        for (int m2 = 0; m2 < 4; ++m2)
#pragma unroll
            for (int nj = 0; nj < 4; ++nj)
                acc[m2][nj] = __builtin_amdgcn_mfma_f32_16x16x32_bf16(
                    afA[m2], bfr[nj], acc[m2][nj], 0, 0, 0);
#pragma unroll
        for (int m2 = 0; m2 < 4; ++m2)
#pragma unroll
            for (int nj = 0; nj < 4; ++nj)
                acc[4 + m2][nj] = __builtin_amdgcn_mfma_f32_16x16x32_bf16(
                    afB[m2], bfr[nj], acc[4 + m2][nj], 0, 0, 0);
        // gate MFMAs: A-operands reused from af registers (blocks 2w, 2w+1).
        // Static 4-way wave-uniform branch; uniform MFMA count/position.
        if (wn == 0) {
            acc_g[0][0] = __builtin_amdgcn_mfma_f32_16x16x32_bf16(afA[0], bg0, acc_g[0][0], 0, 0, 0);
            acc_g[0][1] = __builtin_amdgcn_mfma_f32_16x16x32_bf16(afA[0], bg1, acc_g[0][1], 0, 0, 0);
            acc_g[1][0] = __builtin_amdgcn_mfma_f32_16x16x32_bf16(afA[1], bg0, acc_g[1][0], 0, 0, 0);
            acc_g[1][1] = __builtin_amdgcn_mfma_f32_16x16x32_bf16(afA[1], bg1, acc_g[1][1], 0, 0, 0);
        } else if (wn == 1) {
            acc_g[0][0] = __builtin_amdgcn_mfma_f32_16x16x32_bf16(afA[2], bg0, acc_g[0][0], 0, 0, 0);
            acc_g[0][1] = __builtin_amdgcn_mfma_f32_16x16x32_bf16(afA[2], bg1, acc_g[0][1], 0, 0, 0);
            acc_g[1][0] = __builtin_amdgcn_mfma_f32_16x16x32_bf16(afA[3], bg0, acc_g[1][0], 0, 0, 0);
            acc_g[1][1] = __builtin_amdgcn_mfma_f32_16x16x32_bf16(afA[3], bg1, acc_g[1][1], 0, 0, 0);
        } else if (wn == 2) {
            acc_g[0][0] = __builtin_amdgcn_mfma_f32_16x16x32_bf16(afB[0], bg0, acc_g[0][0], 0, 0, 0);
            acc_g[0][1] = __builtin_amdgcn_mfma_f32_16x16x32_bf16(afB[0], bg1, acc_g[0][1], 0, 0, 0);
            acc_g[1][0] = __builtin_amdgcn_mfma_f32_16x16x32_bf16(afB[1], bg0, acc_g[1][0], 0, 0, 0);
            acc_g[1][1] = __builtin_amdgcn_mfma_f32_16x16x32_bf16(afB[1], bg1, acc_g[1][1], 0, 0, 0);
        } else {
            acc_g[0][0] = __builtin_amdgcn_mfma_f32_16x16x32_bf16(afB[2], bg0, acc_g[0][0], 0, 0, 0);
            acc_g[0][1] = __builtin_amdgcn_mfma_f32_16x16x32_bf16(afB[2], bg1, acc_g[0][1], 0, 0, 0);
            acc_g[1][0] = __builtin_amdgcn_mfma_f32_16x16x32_bf16(afB[3], bg0, acc_g[1][0], 0, 0, 0);
            acc_g[1][1] = __builtin_amdgcn_mfma_f32_16x16x32_bf16(afB[3], bg1, acc_g[1][1], 0, 0, 0);
        }
        __builtin_amdgcn_s_setprio(0);
    }
    __syncthreads();

    // gate -> LDS [256][33] f32 ; gate rows for wave = blocks 2w,2w+1 = rows w*32..+31
    // C/D layout (m89-verified): col = lr, row = lk*4 + r
    float*    gate  = (float*)smem;                 // 33792 B
    unsigned* pscan = (unsigned*)(smem + 36864);    // [513]
    const int s0base = bn >> 3;
#pragma unroll
    for (int ri = 0; ri < 2; ++ri)
#pragma unroll
        for (int ci = 0; ci < 2; ++ci)
#pragma unroll
            for (int r = 0; r < 4; ++r) {
                const int grow = w * 32 + ri * 16 + lk * 4 + r;
                const int gcol = ci * 16 + lr;
                gate[grow * 33 + gcol] = relu_(acc_g[ri][ci][r] + bias0[s0base + gcol]);
            }
    __syncthreads();

    unsigned cnt = 0;
#pragma unroll
    for (int mi = 0; mi < 8; ++mi)
#pragma unroll
        for (int nj = 0; nj < 4; ++nj)
#pragma unroll
            for (int r = 0; r < 4; ++r) {
                const int lrow = wm * 128 + mi * 16 + lk * 4 + r;
                const int lcol = wn * 64 + nj * 16 + lr;
                float v = relu_(acc[mi][nj][r] + bias1[bn + lcol]);
                v *= gate[lrow * 33 + (lcol >> 3)];
                acc[mi][nj][r] = v;
                cnt += (v >= PREF) ? 1u : 0u;
            }
    pscan[t] = cnt;
    __syncthreads();
    for (int s = 1; s < 512; s <<= 1) {
        unsigned v2 = (t >= s) ? pscan[t - s] : 0u;
        __syncthreads();
        pscan[t] += v2;
        __syncthreads();
    }
    if (t == 511) pscan[512] = atomicAdd(&ctrl[0], pscan[511]);
    __syncthreads();
    unsigned off = pscan[512] + pscan[t] - cnt;
#pragma unroll
    for (int mi = 0; mi < 8; ++mi)
#pragma unroll
        for (int nj = 0; nj < 4; ++nj)
#pragma unroll
            for (int r = 0; r < 4; ++r) {
                const float v = acc[mi][nj][r];
                if (v >= PREF) {
                    const int row = bm + wm * 128 + mi * 16 + lk * 4 + r;
                    const int col = bn + wn * 64 + nj * 16 + lr;
                    if (off < CAND_CAP)
                        cand[off] = make_uint2(__float_as_uint(v),
                                               ((unsigned)row << 15) | (unsigned)col);
                    ++off;
                }
            }
}

// ---------------- selection: histograms over candidate float bits ----------------
__global__ void k_hist1(const uint2* __restrict__ cand, unsigned* __restrict__ ctrl) {
    __shared__ unsigned h[2048];
    for (int i = threadIdx.x; i < 2048; i += 256) h[i] = 0;
    __syncthreads();
    unsigned n = umin_(ctrl[0], CAND_CAP);
    for (unsigned i = blockIdx.x * 256 + threadIdx.x; i < n; i += gridDim.x * 256)
        atomicAdd(&h[cand[i].x >> 20], 1u);
    __syncthreads();
    unsigned* hist = ctrl + 256;
    for (int i = threadIdx.x; i < 2048; i += 256)
        if (h[i]) atomicAdd(&hist[i], h[i]);
}

__global__ void k_scan1(unsigned* __restrict__ ctrl) {
    __shared__ unsigned hs[2048];
    __shared__ unsigned cs[256];
    const unsigned* h = ctrl + 256;
    int t = threadIdx.x;
    for (int i = t; i < 2048; i += 256) hs[i] = h[i];
    __syncthreads();
    unsigned s = 0;
    for (int b = 0; b < 8; ++b) s += hs[t * 8 + b];
    cs[t] = s;
    __syncthreads();
    if (t == 0) {
        unsigned cum = 0, T = 0, cb = 0;
        for (int c = 255; c >= 0; --c) {
            if (cum + cs[c] >= KTOT) {
                for (int b = c * 8 + 7; b >= c * 8; --b) {
                    cum += hs[b];
                    if (cum >= KTOT) { T = (unsigned)b; cb = cum - hs[b]; break; }
                }
                break;
            }
            cum += cs[c];
        }
        ctrl[1] = T; ctrl[2] = cb;
    }
}

__global__ void k_hist2(const uint2* __restrict__ cand, unsigned* __restrict__ ctrl) {
    unsigned n = umin_(ctrl[0], CAND_CAP);
    unsigned T = ctrl[1];
    unsigned* hist2 = ctrl + 2304;
    for (unsigned i = blockIdx.x * 256 + threadIdx.x; i < n; i += gridDim.x * 256) {
        unsigned u = cand[i].x;
        if ((u >> 20) == T) atomicAdd(&hist2[(u >> 8) & 0xFFFu], 1u);
    }
}

__global__ void k_scan2(unsigned* __restrict__ ctrl) {
    __shared__ unsigned hs[4096];
    __shared__ unsigned cs[256];
    const unsigned* h = ctrl + 2304;
    int t = threadIdx.x;
    for (int i = t; i < 4096; i += 256) hs[i] = h[i];
    __syncthreads();
    unsigned s = 0;
    for (int b = 0; b < 16; ++b) s += hs[t * 16 + b];
    cs[t] = s;
    __syncthreads();
    if (t == 0) {
        unsigned cum = ctrl[2], T2 = 0;
        for (int c = 255; c >= 0; --c) {
            if (cum + cs[c] >= KTOT) {
                for (int b = c * 16 + 15; b >= c * 16; --b) {
                    cum += hs[b];
                    if (cum >= KTOT) { T2 = (unsigned)b; break; }
                }
                break;
            }
            cum += cs[c];
        }
        ctrl[3] = (ctrl[1] << 12) | T2;   // 24-bit prefix H
    }
}

// fused: count strictly-above band + build their per-row CSR, collect band members
__global__ void k_band_rows(const uint2* __restrict__ cand, unsigned* __restrict__ ctrl,
                            unsigned* __restrict__ rowc, uint2* __restrict__ rowd) {
    __shared__ unsigned lhi;
    if (threadIdx.x == 0) lhi = 0;
    __syncthreads();
    unsigned n = umin_(ctrl[0], CAND_CAP);
    unsigned H = ctrl[3];
    float lo = __uint_as_float(H << 8) - DELTA;
    float hi = __uint_as_float((H + 1u) << 8) + DELTA;
    unsigned* band_idx = ctrl + 6400;
    unsigned my = 0;
    for (unsigned i = blockIdx.x * 256 + threadIdx.x; i < n; i += gridDim.x * 256) {
        uint2 cv = cand[i];
        float v = __uint_as_float(cv.x);
        if (v > hi) {
            ++my;
            unsigned b = cv.y >> 15;
            unsigned p = atomicAdd(&rowc[b], 1u);
            if (p < 256u) rowd[(b << 8) + p] = make_uint2(cv.y & 32767u, cv.x);
        } else if (v >= lo) {
            unsigned p = atomicAdd(&ctrl[5], 1u);
            if (p < BAND_CAP) band_idx[p] = cv.y;
        }
    }
    atomicAdd(&lhi, my);
    __syncthreads();
    if (threadIdx.x == 0 && lhi) atomicAdd(&ctrl[4], lhi);
}

// f64 recompute of band elements (exact-vs-numpy selection values)
__global__ void k_f64(const float* __restrict__ x, const float* __restrict__ b_dec,
                      const float* __restrict__ W0, const float* __restrict__ b0,
                      const float* __restrict__ W1, const float* __restrict__ b1,
                      const unsigned* __restrict__ ctrl, double* __restrict__ band_v) {
    unsigned n = umin_(ctrl[5], BAND_CAP);
    unsigned bi = blockIdx.x;
    if (bi >= n) return;
    const unsigned* band_idx = ctrl + 6400;
    unsigned idx = band_idx[bi];
    int b = idx >> 15, j = idx & 32767, s0 = j >> 3;
    int lane = threadIdx.x;
    const float* xr = x + (size_t)b * DDIM;
    const float* w1 = W1 + (size_t)j * DDIM;
    const float* w0 = W0 + (size_t)s0 * DDIM;
    double d1 = 0.0, d0 = 0.0;
    for (int k = lane; k < DDIM; k += 64) {
        double xv = (double)xr[k] - (double)b_dec[k];
        d1 += xv * (double)w1[k];
        d0 += xv * (double)w0[k];
    }
    for (int off = 32; off; off >>= 1) {
        d1 += __shfl_down(d1, off);
        d0 += __shfl_down(d0, off);
    }
    if (lane == 0) {
        double l1v = d1 + (double)b1[j];  l1v = l1v > 0.0 ? l1v : 0.0;
        double l0v = d0 + (double)b0[s0]; l0v = l0v > 0.0 ? l0v : 0.0;
        band_v[bi] = l1v * l0v;
    }
}

// exact in-band ranking: sort (v64 desc, idx asc) over pow2(n); scatter first
// k_rem directly into the per-row CSR (absorbs old k_rows_b).
__global__ void k_final(unsigned* __restrict__ ctrl, const double* __restrict__ band_v,
                        unsigned* __restrict__ rowc, uint2* __restrict__ rowd) {
    __shared__ unsigned long long skey[BAND_CAP];
    __shared__ unsigned sidx[BAND_CAP];
    int t = threadIdx.x;
    unsigned n = umin_(ctrl[5], BAND_CAP);
    unsigned m = 256; while (m < n) m <<= 1;   // sort size: pow2 >= n (uniform)
    const unsigned* band_idx = ctrl + 6400;
    for (unsigned i = t; i < m; i += 256) {
        if (i < n) {
            skey[i] = (unsigned long long)__double_as_longlong(band_v[i]); // v>=0: monotone bits
            sidx[i] = band_idx[i];
        } else {
            skey[i] = 0ull; sidx[i] = 0xFFFFFFFFu;
        }
    }
    __syncthreads();
    for (unsigned kk = 2; kk <= m; kk <<= 1) {
        for (unsigned jj = kk >> 1; jj > 0; jj >>= 1) {
            for (unsigned i = t; i < m; i += 256) {
                unsigned ixj = i ^ jj;
                if (ixj > i) {
                    unsigned long long ka = skey[i], kb = skey[ixj];
                    unsigned ia = sidx[i], ib = sidx[ixj];
                    bool ab = (ka > kb) || (ka == kb && ia < ib);
                    bool asc = ((i & kk) == 0);
                    if (asc ? !ab : ab) {
                        skey[i] = kb; skey[ixj] = ka;
                        sidx[i] = ib; sidx[ixj] = ia;
                    }
                }
            }
            __syncthreads();
        }
    }
    unsigned c_hi = ctrl[4];
    unsigned k_rem = (c_hi < KTOT) ? (KTOT - c_hi) : 0u;
    if (k_rem > n) k_rem = n;
    for (unsigned i = t; i < k_rem; i += 256) {
        unsigned idx = sidx[i];
        unsigned b = idx >> 15;
        float vf = (float)__longlong_as_double((long long)skey[i]);
        unsigned p = atomicAdd(&rowc[b], 1u);
        if (p < 256u) rowd[(b << 8) + p] = make_uint2(idx & 32767u, __float_as_uint(vf));
    }
}

// decode: out[b,:] = b_dec + sum v * bf16(WdT[j,:]); 192 thr x 4 cols (ushort4)
__launch_bounds__(192) __global__
void k_decode(const uint2* __restrict__ rowd, const unsigned* __restrict__ rowc,
              const unsigned short* __restrict__ WdT, const float* __restrict__ b_dec,
              float* __restrict__ out) {
    __shared__ uint2 e[256];
    int b = blockIdx.x, t = threadIdx.x;
    unsigned c = rowc[b]; if (c > 256u) c = 256u;
    for (int i = t; i < (int)c; i += 192) e[i] = rowd[(b << 8) + i];
    __syncthreads();
    float4 a = *(const float4*)(b_dec + 4 * t);
#pragma unroll 8
    for (unsigned i = 0; i < c; ++i) {
        float v = __uint_as_float(e[i].y);
        ushort4 w4 = *(const ushort4*)(WdT + (size_t)e[i].x * DDIM + 4 * t);
        a.x = fmaf(v, bf2f(w4.x), a.x);
        a.y = fmaf(v, bf2f(w4.y), a.y);
        a.z = fmaf(v, bf2f(w4.z), a.z);
        a.w = fmaf(v, bf2f(w4.w), a.w);
    }
    *(float4*)(out + (size_t)b * DDIM + 4 * t) = a;
}

extern "C" void kernel_launch(void* const* d_in, const int* in_sizes, int n_in,
                              void* d_out, int out_size, void* d_ws, size_t ws_size,
                              hipStream_t stream) {
    const float* x     = (const float*)d_in[0];
    const float* W0    = (const float*)d_in[1];
    const float* b0    = (const float*)d_in[2];
    const float* W1    = (const float*)d_in[3];
    const float* b1    = (const float*)d_in[4];
    const float* Wd    = (const float*)d_in[5];
    const float* b_dec = (const float*)d_in[6];
    float* out = (float*)d_out;

    if (ws_size < WS_NEED) {   // insufficient workspace: fail cleanly
        hipMemsetAsync(d_out, 0, (size_t)out_size * sizeof(float), stream);
        return;
    }

    char* ws = (char*)d_ws;
    short*          XH     = (short*)(ws + OFF_XH);
    short*          XL     = (short*)(ws + OFF_XL);
    short*          W0H    = (short*)(ws + OFF_W0H);
    short*          W0L    = (short*)(ws + OFF_W0L);
    short*          W1H    = (short*)(ws + OFF_W1H);
    short*          W1L    = (short*)(ws + OFF_W1L);
    unsigned short* WdT    = (unsigned short*)(ws + OFF_WDT);  // aliases split region
    unsigned*       ctrl   = (unsigned*)(ws + OFF_CTRL);
    double*         band_v = (double*)(ws + OFF_CTRL + 65536);
    unsigned*       rowc   = (unsigned*)(ws + OFF_ROWC);
    uint2*          rowd   = (uint2*)(ws + OFF_ROWD);
    uint2*          cand   = (uint2*)(ws + OFF_CAND);

    hipMemsetAsync(ctrl, 0, 6400 * sizeof(unsigned), stream);
    hipMemsetAsync(rowc, 0, BROWS * sizeof(unsigned), stream);

    k_split_x<<<(BROWS * DDIM / 4) / 256, 256, 0, stream>>>(x, b_dec, XH, XL);
    k_split_w<<<(S0N * DDIM / 4) / 256, 256, 0, stream>>>(W0, W0H, W0L);
    k_split_w<<<(DICT * DDIM / 4) / 256, 256, 0, stream>>>(W1, W1H, W1L);

    k_mm<<<(DICT / 256) * 16, 512, 0, stream>>>(XH, XL, W1H, W1L, W0H, W0L, b1, b0, cand, ctrl);

    // split region is dead now; WdT (bf16) aliases it
    k_transpose<<<dim3(DICT / 32, DDIM / 32), 256, 0, stream>>>(Wd, WdT);

    k_hist1<<<1024, 256, 0, stream>>>(cand, ctrl);
    k_scan1<<<1, 256, 0, stream>>>(ctrl);
    k_hist2<<<1024, 256, 0, stream>>>(cand, ctrl);
    k_scan2<<<1, 256, 0, stream>>>(ctrl);
    k_band_rows<<<1024, 256, 0, stream>>>(cand, ctrl, rowc, rowd);
    k_f64<<<BAND_CAP, 64, 0, stream>>>(x, b_dec, W0, b0, W1, b1, ctrl, band_v);
    k_final<<<1, 256, 0, stream>>>(ctrl, band_v, rowc, rowd);

    k_decode<<<BROWS, 192, 0, stream>>>(rowd, rowc, WdT, b_dec, out);
}